// Round 5
// baseline (651.927 us; speedup 1.0000x reference)
//
#include <hip/hip_runtime.h>

typedef unsigned short u16;
typedef __attribute__((ext_vector_type(8))) _Float16 f16x8;
typedef __attribute__((ext_vector_type(4))) float f32x4;
typedef __attribute__((ext_vector_type(16))) float f32x16;

#define N_SP 4096
#define C_CH 512
#define B_SZ 4

struct PtrTab { u16* p[4]; };

__device__ __forceinline__ u16 f2h(float f) {
    union { _Float16 h; u16 u; } x; x.h = (_Float16)f; return x.u;
}
__device__ __forceinline__ float h2f(u16 u) {
    union { u16 u; _Float16 h; } x; x.u = u; return (float)x.h;
}
__device__ __forceinline__ void async_cp16(const void* g, void* l) {
    __builtin_amdgcn_global_load_lds((const __attribute__((address_space(1))) unsigned*)g,
                                     (__attribute__((address_space(3))) unsigned*)l, 16, 0, 0);
}
__device__ __forceinline__ float wave_reduce_sum(float v) {
    #pragma unroll
    for (int off = 32; off; off >>= 1) v += __shfl_xor(v, off, 64);
    return v;
}
__device__ __forceinline__ float wave_reduce_max(float v) {
    #pragma unroll
    for (int off = 32; off; off >>= 1) v = fmaxf(v, __shfl_xor(v, off, 64));
    return v;
}
// raw barrier: hardware barrier + compiler memory fence, NO vmcnt drain
__device__ __forceinline__ void bar() { asm volatile("s_barrier" ::: "memory"); }
template<int N> __device__ __forceinline__ void vmwait() {
    if constexpr (N == 0)  asm volatile("s_waitcnt vmcnt(0)" ::: "memory");
    else if constexpr (N == 2)  asm volatile("s_waitcnt vmcnt(2)" ::: "memory");
    else if constexpr (N == 4)  asm volatile("s_waitcnt vmcnt(4)" ::: "memory");
    else if constexpr (N == 6)  asm volatile("s_waitcnt vmcnt(6)" ::: "memory");
    else if constexpr (N == 8)  asm volatile("s_waitcnt vmcnt(8)" ::: "memory");
}
__device__ __forceinline__ void lgkm0() {
    asm volatile("s_waitcnt lgkmcnt(0)" ::: "memory");
    __builtin_amdgcn_sched_barrier(0);
}

// ---- transpose+cast raw x to fp16 [b][n][c], accumulate per-channel partial stats ----
__global__ __launch_bounds__(256) void transpose_cast_stats(
        const float* __restrict__ fc, const float* __restrict__ fs,
        u16* __restrict__ xc, u16* __restrict__ xs,
        float* __restrict__ part_s, float* __restrict__ part_ss) {
    __shared__ float tile[64][65];
    const int t = threadIdx.x;
    const int n0 = blockIdx.x * 64, c0 = blockIdx.y * 64;
    const int z = blockIdx.z;                      // (which<<2)|b
    const int b = z & 3, which = z >> 2;
    const float* src = which ? fs : fc;
    u16* dst = which ? xs : xc;
    const int r = t >> 4, q4 = (t & 15) * 4;
    #pragma unroll
    for (int it = 0; it < 4; ++it) {
        const int row = it * 16 + r;
        float4 v = *(const float4*)(src + ((size_t)b * C_CH + c0 + row) * N_SP + n0 + q4);
        tile[row][q4 + 0] = v.x; tile[row][q4 + 1] = v.y;
        tile[row][q4 + 2] = v.z; tile[row][q4 + 3] = v.w;
    }
    __syncthreads();
    {
        const int cr = t >> 2, q = t & 3;
        float s = 0.f, ss = 0.f;
        #pragma unroll
        for (int i = 0; i < 16; ++i) {
            float a = tile[cr][q * 16 + i];
            s += a; ss += a * a;
        }
        s += __shfl_xor(s, 1, 64);  s += __shfl_xor(s, 2, 64);
        ss += __shfl_xor(ss, 1, 64); ss += __shfl_xor(ss, 2, 64);
        if (q == 0) {
            atomicAdd(&part_s[z * 512 + c0 + cr], s);
            atomicAdd(&part_ss[z * 512 + c0 + cr], ss);
        }
    }
    #pragma unroll
    for (int it = 0; it < 4; ++it) {
        const int nrow = it * 16 + r;
        ushort4 h4;
        h4.x = f2h(tile[q4 + 0][nrow]);
        h4.y = f2h(tile[q4 + 1][nrow]);
        h4.z = f2h(tile[q4 + 2][nrow]);
        h4.w = f2h(tile[q4 + 3][nrow]);
        *(ushort4*)(dst + ((size_t)b * N_SP + n0 + nrow) * C_CH + c0 + q4) = h4;
    }
}

// ---- prep1: weight transpose/cast + finalize stats + wu gemv + bfold gemv ----
// Wbase slots (each 262144 u16): 0 Ws1T, 1 Wcs16, 2 Wc1T, 3 Ws2T, 4 WqT16, 5 Wf16
__global__ __launch_bounds__(256) void prep1(
        const float* __restrict__ W_c1, const float* __restrict__ W_s1,
        const float* __restrict__ W_s2, const float* __restrict__ W_csc,
        const float* __restrict__ b_c1, const float* __restrict__ b_s2,
        const float* __restrict__ b_csc,
        u16* __restrict__ Wbase,
        const float* __restrict__ part_s, const float* __restrict__ part_ss,
        float* __restrict__ mu_a, float* __restrict__ rs_a,
        float* __restrict__ w_u, float* __restrict__ bfold0) {
    __shared__ float tile[64][65];
    const int t = threadIdx.x, z = blockIdx.z;
    if (z < 4) {
        const int n0 = blockIdx.x * 64, c0 = blockIdx.y * 64;
        const float* W = (z == 0) ? W_c1 : (z == 1) ? W_s1 : (z == 2) ? W_s2 : W_csc;
        u16* D = Wbase + ((z == 0) ? 2 : (z == 1) ? 0 : (z == 2) ? 3 : 1) * 262144;
        const int r = t >> 4, q4 = (t & 15) * 4;
        #pragma unroll
        for (int it = 0; it < 4; ++it) {
            const int row = it * 16 + r;
            float4 v = *(const float4*)(W + (size_t)(c0 + row) * 512 + n0 + q4);
            if (z == 3) {
                ushort4 h4 = { f2h(v.x), f2h(v.y), f2h(v.z), f2h(v.w) };
                *(ushort4*)(D + (size_t)(c0 + row) * 512 + n0 + q4) = h4;
            } else {
                tile[row][q4 + 0] = v.x; tile[row][q4 + 1] = v.y;
                tile[row][q4 + 2] = v.z; tile[row][q4 + 3] = v.w;
            }
        }
        __syncthreads();
        if (z == 3) return;
        #pragma unroll
        for (int it = 0; it < 4; ++it) {
            const int nrow = it * 16 + r;
            ushort4 h4;
            h4.x = f2h(tile[q4 + 0][nrow]);
            h4.y = f2h(tile[q4 + 1][nrow]);
            h4.z = f2h(tile[q4 + 2][nrow]);
            h4.w = f2h(tile[q4 + 3][nrow]);
            *(ushort4*)(D + (size_t)(n0 + nrow) * 512 + c0 + q4) = h4;
        }
        return;
    }
    const int flat = blockIdx.y * 8 + blockIdx.x;
    if (flat < 8) {               // finalize stats
        #pragma unroll
        for (int h = 0; h < 2; ++h) {
            const int c = flat * 512 + h * 256 + t;
            const float S = part_s[c], SS = part_ss[c];
            const float mean = S * (1.f / N_SP);
            const float var = (SS - S * mean) * (1.f / (N_SP - 1));
            mu_a[c] = mean;
            rs_a[c] = rsqrtf(var + 1e-5f);
        }
    } else if (flat < 10) {       // w_u[d] = sum_o b_c1[o] W_s1[o][d]
        const int d = (flat - 8) * 256 + t;
        float acc = 0.f;
        for (int o = 0; o < 512; ++o) acc += b_c1[o] * W_s1[(size_t)o * 512 + d];
        w_u[d] = acc;
    } else if (flat < 42) {       // bfold0[o] = sum_c W_csc[o][c] b_s2[c] + b_csc[o]
        const int w4 = t >> 6, l = t & 63;
        #pragma unroll
        for (int q = 0; q < 4; ++q) {
            const int o = (flat - 10) * 16 + w4 * 4 + q;
            const float4 w0 = *(const float4*)(W_csc + (size_t)o * 512 + l * 8);
            const float4 w1 = *(const float4*)(W_csc + (size_t)o * 512 + l * 8 + 4);
            const float4 b0 = *(const float4*)(b_s2 + l * 8);
            const float4 b1 = *(const float4*)(b_s2 + l * 8 + 4);
            float acc = w0.x * b0.x + w0.y * b0.y + w0.z * b0.z + w0.w * b0.w
                      + w1.x * b1.x + w1.y * b1.y + w1.z * b1.z + w1.w * b1.w;
            acc = wave_reduce_sum(acc);
            if (l == 0) bfold0[o] = acc + b_csc[o];
        }
    }
}

// ---- prep2: make_scaled + bias2 + u_big, one launch (grid 2304) ----
__global__ __launch_bounds__(256) void prep2(
        const u16* __restrict__ WqT16, const u16* __restrict__ Wf16,
        const u16* __restrict__ xs,
        const float* __restrict__ mu_a, const float* __restrict__ rs_a,
        const float* __restrict__ bfold0, const float* __restrict__ w_u,
        u16* __restrict__ Wq_z, u16* __restrict__ Wf_z,
        float* __restrict__ bq, float* __restrict__ bh, float* __restrict__ u_) {
    const int id = blockIdx.x, t = threadIdx.x;
    if (id < 1024) {              // make_scaled
        const int y = id >> 9;
        const size_t e = ((size_t)(id & 511) * 256 + t) * 8;
        const int z = (int)(e >> 18), rem = (int)(e & 262143);
        const int d = rem >> 9, a0 = rem & 511;
        u16 v[8];
        if (y == 0) {
            *(uint4*)v = *(const uint4*)(WqT16 + rem);
            const float rd = rs_a[(4 + z) * 512 + d];
            const float* rc = rs_a + z * 512 + a0;
            #pragma unroll
            for (int i = 0; i < 8; ++i) v[i] = f2h(h2f(v[i]) * rc[i] * rd);
            *(uint4*)(Wq_z + e) = *(const uint4*)v;
        } else {
            *(uint4*)v = *(const uint4*)(Wf16 + rem);
            const float* rk = rs_a + (4 + z) * 512 + a0;
            #pragma unroll
            for (int i = 0; i < 8; ++i) v[i] = f2h(h2f(v[i]) * rk[i]);
            *(uint4*)(Wf_z + e) = *(const uint4*)v;
        }
    } else if (id < 2048) {       // bias2
        const int w = t >> 6, l = t & 63;
        const int oid = (id - 1024) * 4 + w;
        const int kind = oid >> 11;
        const int z = (oid >> 9) & 3, d = oid & 511;
        const u16* row = (kind == 0 ? WqT16 : Wf16) + (size_t)d * 512;
        const int sb = (kind == 0 ? z : 4 + z) * 512;
        float acc = 0.f;
        #pragma unroll
        for (int i = 0; i < 8; ++i) {
            const int a = l * 8 + i;
            acc += h2f(row[a]) * mu_a[sb + a] * rs_a[sb + a];
        }
        acc = wave_reduce_sum(acc);
        if (l == 0) {
            if (kind == 0) bq[z * 512 + d] = -acc * rs_a[(4 + z) * 512 + d];
            else           bh[z * 512 + d] = bfold0[d] - acc;
        }
    } else {                      // u_big
        const int id2 = id - 2048;                 // 0..255
        const int b = id2 >> 6, xblk = id2 & 63;
        const int w = t >> 6, l = t & 63;
        float4 u0 = *(const float4*)(w_u + l * 8);
        float4 u1 = *(const float4*)(w_u + l * 8 + 4);
        const float4 r0 = *(const float4*)(rs_a + (4 + b) * 512 + l * 8);
        const float4 r1 = *(const float4*)(rs_a + (4 + b) * 512 + l * 8 + 4);
        u0.x *= r0.x; u0.y *= r0.y; u0.z *= r0.z; u0.w *= r0.w;
        u1.x *= r1.x; u1.y *= r1.y; u1.z *= r1.z; u1.w *= r1.w;
        #pragma unroll
        for (int jj = 0; jj < 16; ++jj) {
            const int j = xblk * 64 + w * 16 + jj;
            const u16* row = xs + ((size_t)b * N_SP + j) * C_CH + l * 8;
            f16x8 x = *(const f16x8*)row;
            float acc = (float)x[0] * u0.x + (float)x[1] * u0.y + (float)x[2] * u0.z + (float)x[3] * u0.w
                      + (float)x[4] * u1.x + (float)x[5] * u1.y + (float)x[6] * u1.z + (float)x[7] * u1.w;
            acc = wave_reduce_sum(acc);
            if (l == 0) u_[(size_t)b * N_SP + j] = acc;
        }
    }
}

// ---------------- legacy 4-wave GEMM (32x32x16): kept only for the small 512^3 weight GEMM ----
enum { OUT_F32 = 0, OUT_F16 = 1 };

template<int OUTMODE, bool TABB, bool TABD, int MI, int MJ>
__global__ __launch_bounds__(256) void gemm_bt(
    const u16* __restrict__ A, const u16* __restrict__ B, PtrTab tab,
    float* __restrict__ Df, u16* __restrict__ Dh,
    const float* __restrict__ bias_m, const float* __restrict__ bias_n,
    const float* __restrict__ res,
    int M, int N, int K, int lda, int ldb, int ldd,
    size_t sA, size_t sB, size_t sD, size_t sR, int sBm, int sBn)
{
    constexpr int TM = MI * 64, TN = MJ * 64, BK = 64;
    constexpr int AITS = (TM * BK) / (256 * 8);
    constexpr int BITS = (TN * BK) / (256 * 8);
    __shared__ u16 smem[(TM + TN) * BK];
    u16* As = smem;
    u16* Bs = smem + TM * BK;

    const int t = threadIdx.x;
    const int l = t & 63, w = t >> 6;
    const int m0 = blockIdx.y * TM, n0 = blockIdx.x * TN;
    const size_t zb = blockIdx.z;
    const u16* pA = A + zb * sA + (size_t)m0 * lda;
    const u16* pB = (TABB ? tab.p[zb] : B + zb * sB) + (size_t)n0 * ldb;

    const int wr = (w & 1) * (MI * 32), wc = (w >> 1) * (MJ * 32);

    f32x16 acc[MI][MJ] = {};

    for (int k0 = 0; k0 < K; k0 += BK) {
        #pragma unroll
        for (int it = 0; it < AITS; ++it) {
            const int L = it * 256 + t;
            const int row = L >> 3, c = L & 7;
            const int sc = (c ^ (row & 7)) * 8;
            async_cp16(pA + (size_t)row * lda + k0 + sc, As + L * 8);
        }
        #pragma unroll
        for (int it = 0; it < BITS; ++it) {
            const int L = it * 256 + t;
            const int row = L >> 3, c = L & 7;
            const int sc = (c ^ (row & 7)) * 8;
            async_cp16(pB + (size_t)row * ldb + k0 + sc, Bs + L * 8);
        }
        __syncthreads();
        #pragma unroll
        for (int kk = 0; kk < 4; ++kk) {
            f16x8 af[MI], bf[MJ];
            #pragma unroll
            for (int i = 0; i < MI; ++i) {
                const int row = wr + i * 32 + (l & 31);
                const int ch = ((kk * 2 + (l >> 5)) ^ (row & 7)) * 8;
                af[i] = *(const f16x8*)(As + row * BK + ch);
            }
            #pragma unroll
            for (int j = 0; j < MJ; ++j) {
                const int row = wc + j * 32 + (l & 31);
                const int ch = ((kk * 2 + (l >> 5)) ^ (row & 7)) * 8;
                bf[j] = *(const f16x8*)(Bs + row * BK + ch);
            }
            #pragma unroll
            for (int i = 0; i < MI; ++i)
                #pragma unroll
                for (int j = 0; j < MJ; ++j)
                    acc[i][j] = __builtin_amdgcn_mfma_f32_32x32x16_f16(af[i], bf[j], acc[i][j], 0, 0, 0);
        }
        __syncthreads();
    }

    const int cl = l & 31, rh = (l >> 5) * 4;
    u16* pDh = (OUTMODE == OUT_F16) ? (TABD ? tab.p[zb] : Dh + zb * sD) : nullptr;
    float* pDf = (OUTMODE == OUT_F32) ? (Df + zb * sD) : nullptr;
    #pragma unroll
    for (int i = 0; i < MI; ++i) {
        #pragma unroll
        for (int j = 0; j < MJ; ++j) {
            const int nn = n0 + wc + j * 32 + cl;
            const float bn = bias_n ? bias_n[(size_t)sBn * zb + nn] : 0.f;
            #pragma unroll
            for (int reg = 0; reg < 16; ++reg) {
                const int ml = (reg & 3) + 8 * (reg >> 2) + rh;
                const int mm = m0 + wr + i * 32 + ml;
                float v = acc[i][j][reg] + bn;
                if (bias_m) v += bias_m[(size_t)sBm * zb + mm];
                const size_t off = (size_t)mm * ldd + nn;
                if (OUTMODE == OUT_F32) {
                    if (res) v += res[zb * sR + off];
                    pDf[off] = v;
                } else {
                    pDh[off] = f2h(v);
                }
            }
        }
    }
}

// ======== 8-wave 4-phase reg-staged GEMM, 16x16x32, PADDED LDS (conflict-free) ========
// BM x 256 tile, BK=64, 512 threads = 8 waves (2 row x 4 col), wave tile (BM/2) x 64.
// LDS rows padded: row stride RS = 72 elems (144 B) -> bank rotation 4/row -> frag
// ds_read_b128 is 2-way max (free, m136). Padding requires reg-staging (gload_lds
// can't scatter): global->uint4 regs at p0 (coalesced), vmcnt-guarded ds_write_b128
// at p2 (A) / p3 (B) into the nxt buffer -- ~3 phases (>2000 cy) of flight cover.
// Phase tour (A0B0)(A0B1)(A1B1)(A1B0): holds A across phase pairs, re-reads only B0
// (4 reads) -- 28 (BM=256) / 20 (BM=128) reads per wave per K-tile.
// Per phase: reads -> [stage op] -> lgkmcnt(0)+sched_barrier (rule 18) -> setprio(1)
// MFMA cluster setprio(0) -> s_barrier. Hazards: all W target nxt; reads target cur;
// each wave's own lgkm0 before the trailing barrier makes W visible block-wide.
template<int OUTMODE, bool TABB, bool TABD, int BM>
__global__ __launch_bounds__(512, 2) void gemm_rs(
    const u16* __restrict__ A, const u16* __restrict__ B, PtrTab tab,
    float* __restrict__ Df, u16* __restrict__ Dh,
    const float* __restrict__ bias_m, const float* __restrict__ bias_n,
    const float* __restrict__ res,
    int K, int lda, int ldb, int ldd,
    size_t sA, size_t sB, size_t sD, size_t sR, int sBm, int sBn)
{
    constexpr int BN = 256, BK = 64, RS = BK + 8;   // padded row stride (u16 elems)
    constexpr int HM = BM / 2;                       // A-half rows
    constexpr int MF = BM / 64;                      // 16-row m-frags per quadrant per wave
    constexpr int GA = BM / 64;                      // uint4 gloads/thread for all of A
    constexpr int GB = BN / 64;                      // ... for all of B (=4)
    constexpr int BUF = (BM + BN) * RS;              // u16 per tile buffer
    __shared__ u16 smem[2 * BUF];

    const int t = threadIdx.x;
    const int l = t & 63, w = t >> 6;
    const int m0 = blockIdx.y * BM, n0 = blockIdx.x * BN;
    const size_t zb = blockIdx.z;
    const u16* pA = A + zb * sA + (size_t)m0 * lda;
    const u16* pB = (TABB ? tab.p[zb] : B + zb * sB) + (size_t)n0 * ldb;

    const int wr = (w & 1) * (HM / 2);    // wave row offset within an A-half
    const int wc = (w >> 1) * 32;         // wave col offset within a B-half (128)

    f32x4 acc[2 * MF][4] = {};
    uint4 rg[GA + GB];

    auto gloadA = [&](int k0) {
        #pragma unroll
        for (int i = 0; i < GA; ++i) {
            const int L = i * 512 + t, row = L >> 3, c = L & 7;
            rg[i] = *(const uint4*)(pA + (size_t)row * lda + k0 + c * 8);
        }
    };
    auto gloadB = [&](int k0) {
        #pragma unroll
        for (int i = 0; i < GB; ++i) {
            const int L = i * 512 + t, row = L >> 3, c = L & 7;
            rg[GA + i] = *(const uint4*)(pB + (size_t)row * ldb + k0 + c * 8);
        }
    };
    auto wldsA = [&](int buf) {
        u16* dA = smem + buf * BUF;
        #pragma unroll
        for (int i = 0; i < GA; ++i) {
            const int L = i * 512 + t, row = L >> 3, c = L & 7;
            *(uint4*)(dA + row * RS + c * 8) = rg[i];
        }
    };
    auto wldsB = [&](int buf) {
        u16* dB = smem + buf * BUF + BM * RS;
        #pragma unroll
        for (int i = 0; i < GB; ++i) {
            const int L = i * 512 + t, row = L >> 3, c = L & 7;
            *(uint4*)(dB + row * RS + c * 8) = rg[GA + i];
        }
    };
    auto rdA = [&](const u16* As, int qi, int mf, int kk) -> f16x8 {
        const int row = qi * HM + wr + mf * 16 + (l & 15);
        const int ch = kk * 4 + (l >> 4);
        return *(const f16x8*)(As + row * RS + ch * 8);
    };
    auto rdB = [&](const u16* Bs, int qj, int nf, int kk) -> f16x8 {
        const int row = qj * 128 + wc + nf * 16 + (l & 15);
        const int ch = kk * 4 + (l >> 4);
        return *(const f16x8*)(Bs + row * RS + ch * 8);
    };

    f16x8 af[MF][2], bf[2][2];

    const int NT = K / BK;
    // prologue: tile 0 fully staged (drained once — outside steady state)
    gloadA(0); gloadB(0);
    vmwait<0>();
    wldsA(0); wldsB(0);
    lgkm0();
    bar();

    for (int tl = 0; tl < NT; ++tl) {
        const int cur = tl & 1, nxt = cur ^ 1;
        const u16* As = smem + cur * BUF;
        const u16* Bs = As + BM * RS;
        const int k1 = (tl + 1) * BK;
        const bool pf = (tl + 1 < NT);

        // ---- phase 0: A0 x B0 -> acc[mf][nf]; issue next tile's gloads ----
        #pragma unroll
        for (int mf = 0; mf < MF; ++mf) { af[mf][0] = rdA(As, 0, mf, 0); af[mf][1] = rdA(As, 0, mf, 1); }
        #pragma unroll
        for (int nf = 0; nf < 2; ++nf) { bf[nf][0] = rdB(Bs, 0, nf, 0); bf[nf][1] = rdB(Bs, 0, nf, 1); }
        if (pf) { gloadA(k1); gloadB(k1); }
        lgkm0();
        __builtin_amdgcn_s_setprio(1);
        #pragma unroll
        for (int mf = 0; mf < MF; ++mf)
            #pragma unroll
            for (int nf = 0; nf < 2; ++nf) {
                acc[mf][nf] = __builtin_amdgcn_mfma_f32_16x16x32_f16(af[mf][0], bf[nf][0], acc[mf][nf], 0, 0, 0);
                acc[mf][nf] = __builtin_amdgcn_mfma_f32_16x16x32_f16(af[mf][1], bf[nf][1], acc[mf][nf], 0, 0, 0);
            }
        __builtin_amdgcn_s_setprio(0);
        bar();

        // ---- phase 1: A0 (held) x B1 -> acc[mf][2+nf] ----
        #pragma unroll
        for (int nf = 0; nf < 2; ++nf) { bf[nf][0] = rdB(Bs, 1, nf, 0); bf[nf][1] = rdB(Bs, 1, nf, 1); }
        lgkm0();
        __builtin_amdgcn_s_setprio(1);
        #pragma unroll
        for (int mf = 0; mf < MF; ++mf)
            #pragma unroll
            for (int nf = 0; nf < 2; ++nf) {
                acc[mf][2 + nf] = __builtin_amdgcn_mfma_f32_16x16x32_f16(af[mf][0], bf[nf][0], acc[mf][2 + nf], 0, 0, 0);
                acc[mf][2 + nf] = __builtin_amdgcn_mfma_f32_16x16x32_f16(af[mf][1], bf[nf][1], acc[mf][2 + nf], 0, 0, 0);
            }
        __builtin_amdgcn_s_setprio(0);
        bar();

        // ---- phase 2: A1 x B1 (held) -> acc[MF+mf][2+nf]; write A(next) to LDS ----
        #pragma unroll
        for (int mf = 0; mf < MF; ++mf) { af[mf][0] = rdA(As, 1, mf, 0); af[mf][1] = rdA(As, 1, mf, 1); }
        if (pf) { vmwait<GB>(); wldsA(nxt); }     // A-gloads (oldest) done; B stays in flight
        lgkm0();
        __builtin_amdgcn_s_setprio(1);
        #pragma unroll
        for (int mf = 0; mf < MF; ++mf)
            #pragma unroll
            for (int nf = 0; nf < 2; ++nf) {
                acc[MF + mf][2 + nf] = __builtin_amdgcn_mfma_f32_16x16x32_f16(af[mf][0], bf[nf][0], acc[MF + mf][2 + nf], 0, 0, 0);
                acc[MF + mf][2 + nf] = __builtin_amdgcn_mfma_f32_16x16x32_f16(af[mf][1], bf[nf][1], acc[MF + mf][2 + nf], 0, 0, 0);
            }
        __builtin_amdgcn_s_setprio(0);
        bar();

        // ---- phase 3: A1 (held) x B0 (re-read) -> acc[MF+mf][nf]; write B(next) ----
        #pragma unroll
        for (int nf = 0; nf < 2; ++nf) { bf[nf][0] = rdB(Bs, 0, nf, 0); bf[nf][1] = rdB(Bs, 0, nf, 1); }
        if (pf) { vmwait<0>(); wldsB(nxt); }
        lgkm0();
        __builtin_amdgcn_s_setprio(1);
        #pragma unroll
        for (int mf = 0; mf < MF; ++mf)
            #pragma unroll
            for (int nf = 0; nf < 2; ++nf) {
                acc[MF + mf][nf] = __builtin_amdgcn_mfma_f32_16x16x32_f16(af[mf][0], bf[nf][0], acc[MF + mf][nf], 0, 0, 0);
                acc[MF + mf][nf] = __builtin_amdgcn_mfma_f32_16x16x32_f16(af[mf][1], bf[nf][1], acc[MF + mf][nf], 0, 0, 0);
            }
        __builtin_amdgcn_s_setprio(0);
        bar();
    }

    // C/D (16x16): col = lane&15, row = (lane>>4)*4 + reg   (validated r3)
    const int cl = l & 15, rh = (l >> 4) * 4;
    u16* pDh = (OUTMODE == OUT_F16) ? (TABD ? tab.p[zb] : Dh + zb * sD) : nullptr;
    float* pDf = (OUTMODE == OUT_F32) ? (Df + zb * sD) : nullptr;
    #pragma unroll
    for (int qi = 0; qi < 2; ++qi) {
        #pragma unroll
        for (int qj = 0; qj < 2; ++qj) {
            #pragma unroll
            for (int mf = 0; mf < MF; ++mf) {
                #pragma unroll
                for (int nf = 0; nf < 2; ++nf) {
                    const int nn = n0 + qj * 128 + wc + nf * 16 + cl;
                    const float bn = bias_n ? bias_n[(size_t)sBn * zb + nn] : 0.f;
                    const f32x4 a4 = acc[qi * MF + mf][qj * 2 + nf];
                    #pragma unroll
                    for (int reg = 0; reg < 4; ++reg) {
                        const int mm = m0 + qi * HM + wr + mf * 16 + rh + reg;
                        float v = a4[reg] + bn;
                        if (bias_m) v += bias_m[(size_t)sBm * zb + mm];
                        const size_t off = (size_t)mm * ldd + nn;
                        if (OUTMODE == OUT_F32) {
                            if (res) v += res[zb * sR + off];
                            pDf[off] = v;
                        } else {
                            pDh[off] = f2h(v);
                        }
                    }
                }
            }
        }
    }
}

// ---------------- softmax row-wise, fp16 in-place ----------------
__global__ __launch_bounds__(256) void softmax_kernel(PtrTab tab) {
    u16* row = tab.p[blockIdx.y] + (size_t)blockIdx.x * N_SP;
    const int t = threadIdx.x;
    u16 raw[16];
    *(uint4*)(raw + 0) = *(const uint4*)(row + t * 16);
    *(uint4*)(raw + 8) = *(const uint4*)(row + t * 16 + 8);
    float v[16];
    float mx = -1e30f;
    #pragma unroll
    for (int i = 0; i < 16; ++i) { v[i] = h2f(raw[i]); mx = fmaxf(mx, v[i]); }
    mx = wave_reduce_max(mx);
    __shared__ float red[4];
    const int wave = t >> 6;
    if ((t & 63) == 0) red[wave] = mx;
    __syncthreads();
    mx = fmaxf(fmaxf(red[0], red[1]), fmaxf(red[2], red[3]));
    float sum = 0.f;
    #pragma unroll
    for (int i = 0; i < 16; ++i) { v[i] = __expf(v[i] - mx); sum += v[i]; }
    sum = wave_reduce_sum(sum);
    __syncthreads();
    if ((t & 63) == 0) red[wave] = sum;
    __syncthreads();
    const float inv = 1.f / (red[0] + red[1] + red[2] + red[3]);
    #pragma unroll
    for (int i = 0; i < 16; ++i) raw[i] = f2h(v[i] * inv);
    *(uint4*)(row + t * 16)     = *(const uint4*)(raw + 0);
    *(uint4*)(row + t * 16 + 8) = *(const uint4*)(raw + 8);
}

extern "C" void kernel_launch(void* const* d_in, const int* in_sizes, int n_in,
                              void* d_out, int out_size, void* d_ws, size_t ws_size,
                              hipStream_t stream) {
    const float* f_c   = (const float*)d_in[0];
    const float* f_s   = (const float*)d_in[1];
    const float* W_c1  = (const float*)d_in[2];
    const float* b_c1  = (const float*)d_in[3];
    const float* W_s1  = (const float*)d_in[4];
    const float* b_s1  = (const float*)d_in[5]; (void)b_s1;   // softmax-invariant, dropped
    const float* W_s2  = (const float*)d_in[6];
    const float* b_s2  = (const float*)d_in[7];
    const float* W_csc = (const float*)d_in[8];
    const float* b_csc = (const float*)d_in[9];

    const size_t PB = (size_t)N_SP * C_CH;      // 2M elems per batch plane
    const size_t M1 = 1024 * 1024;

    u16* ws   = (u16*)d_ws;
    u16* Xs   = ws;                 // raw fp16 [b][j][c]   0..8M
    u16* q_   = ws + 8 * M1;        // q'[b][i][d]          8..16M
    u16* hc   = ws + 16 * M1;       // hc[b][o][j]          16..24M
    u16* Xc   = ws + 24 * M1;       // raw fp16 (dead after q'-conv; S3 aliases)
    u16* S3   = ws + 24 * M1;
    u16* S0   = ws + 40 * M1;
    u16* S1   = ws + 56 * M1;
    u16* S2   = ws + 72 * M1;
    u16* Wbase= ws + 88 * M1;       // 6 x 262144: Ws1T, Wcs16, Wc1T, Ws2T, WqT16, Wf16
    u16* WqT16= Wbase + 4 * 262144;
    u16* Wf16 = Wbase + 5 * 262144;
    u16* Wq_z = Wbase + 6 * 262144; // 4 x 256K
    u16* Wf_z = Wq_z + 1048576;     // 4 x 256K
    float* f32b = (float*)(ws + 92 * M1);
    float* part_s  = f32b;          // 4096
    float* part_ss = f32b + 4096;
    float* mu_a    = f32b + 8192;
    float* rs_a    = f32b + 12288;
    float* w_u     = f32b + 16384;  // 512
    float* bfold0  = f32b + 16896;  // 512
    float* bq      = f32b + 17408;  // 2048
    float* bh      = f32b + 19456;  // 2048
    float* u_      = f32b + 21504;  // 4*4096

    PtrTab Stab; Stab.p[0] = S0; Stab.p[1] = S1; Stab.p[2] = S2; Stab.p[3] = S3;
    PtrTab tab0 = Stab;

    hipMemsetAsync(part_s, 0, 2 * 4096 * sizeof(float), stream);

    transpose_cast_stats<<<dim3(64, 8, 8), 256, 0, stream>>>(f_c, f_s, Xc, Xs, part_s, part_ss);

    // weight transforms + stats finalize + small gemvs, one launch
    prep1<<<dim3(8, 8, 5), 256, 0, stream>>>(W_c1, W_s1, W_s2, W_csc, b_c1, b_s2, b_csc,
                                             Wbase, part_s, part_ss, mu_a, rs_a, w_u, bfold0);

    // WqT[d][a] = sum_o Ws1T[d][o] Wc1T[a][o]; Wfold[o][k] = sum_c Wcs16[o][c] Ws2T[k][c]
    gemm_bt<OUT_F16, false, false, 2, 2><<<dim3(4, 4, 2), 256, 0, stream>>>(
        Wbase, Wbase + 2 * 262144, tab0, nullptr, WqT16, nullptr, nullptr, nullptr,
        512, 512, 512, 512, 512, 512, 262144, 262144, 262144, 0, 0, 0);

    // per-batch scaled weights + folded biases + u vector, one launch
    prep2<<<2304, 256, 0, stream>>>(WqT16, Wf16, Xs, mu_a, rs_a, bfold0, w_u,
                                    Wq_z, Wf_z, bq, bh, u_);

    // q'[b][i][d] = sum_a Xc_raw[b][i][a] Wq_z[b][d][a] + bq[b][d]
    gemm_rs<OUT_F16, false, false, 128><<<dim3(2, 32, B_SZ), 512, 0, stream>>>(
        Xc, Wq_z, tab0, nullptr, q_, nullptr, bq, nullptr,
        C_CH, C_CH, C_CH, C_CH, PB, 262144, PB, 0, 0, 512);
    // hc[b][o][j] = sum_k Wf_z[b][o][k] Xs_raw[b][j][k] + bh[b][o]
    gemm_rs<OUT_F16, false, false, 128><<<dim3(16, 4, B_SZ), 512, 0, stream>>>(
        Wf_z, Xs, tab0, nullptr, hc, bh, nullptr, nullptr,
        C_CH, C_CH, C_CH, N_SP, 262144, PB, PB, 0, 512, 0);

    // S_b[i][j] = sum_d q'[i][d] Xs_raw[j][d] + u[b][j]
    gemm_rs<OUT_F16, false, true, 256><<<dim3(16, 16, B_SZ), 512, 0, stream>>>(
        q_, Xs, Stab, nullptr, nullptr, nullptr, u_, nullptr,
        C_CH, C_CH, C_CH, N_SP, PB, PB, 0, 0, 0, N_SP);

    softmax_kernel<<<dim3(N_SP, B_SZ), 256, 0, stream>>>(Stab);

    // out[b][o][i] = sum_j hc[o][j] P[i][j] + f_c
    gemm_rs<OUT_F32, true, false, 128><<<dim3(16, 4, B_SZ), 512, 0, stream>>>(
        hc, nullptr, Stab, (float*)d_out, nullptr, nullptr, nullptr, f_c,
        N_SP, N_SP, N_SP, N_SP, PB, 0, PB, PB, 0, 0);
}

// Round 7
// 448.501 us; speedup vs baseline: 1.4536x; 1.4536x over previous
//
#include <hip/hip_runtime.h>

typedef unsigned short u16;
typedef __attribute__((ext_vector_type(8))) _Float16 f16x8;
typedef __attribute__((ext_vector_type(4))) float f32x4;
typedef __attribute__((ext_vector_type(16))) float f32x16;

#define N_SP 4096
#define C_CH 512
#define B_SZ 4

struct PtrTab { u16* p[4]; };

__device__ __forceinline__ u16 f2h(float f) {
    union { _Float16 h; u16 u; } x; x.h = (_Float16)f; return x.u;
}
__device__ __forceinline__ float h2f(u16 u) {
    union { u16 u; _Float16 h; } x; x.u = u; return (float)x.h;
}
__device__ __forceinline__ void async_cp16(const void* g, void* l) {
    __builtin_amdgcn_global_load_lds((const __attribute__((address_space(1))) unsigned*)g,
                                     (__attribute__((address_space(3))) unsigned*)l, 16, 0, 0);
}
__device__ __forceinline__ float wave_reduce_sum(float v) {
    #pragma unroll
    for (int off = 32; off; off >>= 1) v += __shfl_xor(v, off, 64);
    return v;
}
__device__ __forceinline__ float wave_reduce_max(float v) {
    #pragma unroll
    for (int off = 32; off; off >>= 1) v = fmaxf(v, __shfl_xor(v, off, 64));
    return v;
}
// raw barrier: hardware barrier + compiler memory fence, NO vmcnt drain
__device__ __forceinline__ void bar() { asm volatile("s_barrier" ::: "memory"); }
template<int N> __device__ __forceinline__ void vmwait() {
    if constexpr (N == 0)  asm volatile("s_waitcnt vmcnt(0)" ::: "memory");
    else if constexpr (N == 2)  asm volatile("s_waitcnt vmcnt(2)" ::: "memory");
    else if constexpr (N == 4)  asm volatile("s_waitcnt vmcnt(4)" ::: "memory");
    else if constexpr (N == 6)  asm volatile("s_waitcnt vmcnt(6)" ::: "memory");
    else if constexpr (N == 8)  asm volatile("s_waitcnt vmcnt(8)" ::: "memory");
}
__device__ __forceinline__ void lgkm0() {
    asm volatile("s_waitcnt lgkmcnt(0)" ::: "memory");
    __builtin_amdgcn_sched_barrier(0);
}

// ---- transpose+cast raw x to fp16 [b][n][c], accumulate per-channel partial stats ----
__global__ __launch_bounds__(256) void transpose_cast_stats(
        const float* __restrict__ fc, const float* __restrict__ fs,
        u16* __restrict__ xc, u16* __restrict__ xs,
        float* __restrict__ part_s, float* __restrict__ part_ss) {
    __shared__ float tile[64][65];
    const int t = threadIdx.x;
    const int n0 = blockIdx.x * 64, c0 = blockIdx.y * 64;
    const int z = blockIdx.z;                      // (which<<2)|b
    const int b = z & 3, which = z >> 2;
    const float* src = which ? fs : fc;
    u16* dst = which ? xs : xc;
    const int r = t >> 4, q4 = (t & 15) * 4;
    #pragma unroll
    for (int it = 0; it < 4; ++it) {
        const int row = it * 16 + r;
        float4 v = *(const float4*)(src + ((size_t)b * C_CH + c0 + row) * N_SP + n0 + q4);
        tile[row][q4 + 0] = v.x; tile[row][q4 + 1] = v.y;
        tile[row][q4 + 2] = v.z; tile[row][q4 + 3] = v.w;
    }
    __syncthreads();
    {
        const int cr = t >> 2, q = t & 3;
        float s = 0.f, ss = 0.f;
        #pragma unroll
        for (int i = 0; i < 16; ++i) {
            float a = tile[cr][q * 16 + i];
            s += a; ss += a * a;
        }
        s += __shfl_xor(s, 1, 64);  s += __shfl_xor(s, 2, 64);
        ss += __shfl_xor(ss, 1, 64); ss += __shfl_xor(ss, 2, 64);
        if (q == 0) {
            atomicAdd(&part_s[z * 512 + c0 + cr], s);
            atomicAdd(&part_ss[z * 512 + c0 + cr], ss);
        }
    }
    #pragma unroll
    for (int it = 0; it < 4; ++it) {
        const int nrow = it * 16 + r;
        ushort4 h4;
        h4.x = f2h(tile[q4 + 0][nrow]);
        h4.y = f2h(tile[q4 + 1][nrow]);
        h4.z = f2h(tile[q4 + 2][nrow]);
        h4.w = f2h(tile[q4 + 3][nrow]);
        *(ushort4*)(dst + ((size_t)b * N_SP + n0 + nrow) * C_CH + c0 + q4) = h4;
    }
}

// ---- prep1: weight transpose/cast + finalize stats + wu gemv + bfold gemv ----
// Wbase slots (each 262144 u16): 0 Ws1T, 1 Wcs16, 2 Wc1T, 3 Ws2T, 4 WqT16, 5 Wf16
__global__ __launch_bounds__(256) void prep1(
        const float* __restrict__ W_c1, const float* __restrict__ W_s1,
        const float* __restrict__ W_s2, const float* __restrict__ W_csc,
        const float* __restrict__ b_c1, const float* __restrict__ b_s2,
        const float* __restrict__ b_csc,
        u16* __restrict__ Wbase,
        const float* __restrict__ part_s, const float* __restrict__ part_ss,
        float* __restrict__ mu_a, float* __restrict__ rs_a,
        float* __restrict__ w_u, float* __restrict__ bfold0) {
    __shared__ float tile[64][65];
    const int t = threadIdx.x, z = blockIdx.z;
    if (z < 4) {
        const int n0 = blockIdx.x * 64, c0 = blockIdx.y * 64;
        const float* W = (z == 0) ? W_c1 : (z == 1) ? W_s1 : (z == 2) ? W_s2 : W_csc;
        u16* D = Wbase + ((z == 0) ? 2 : (z == 1) ? 0 : (z == 2) ? 3 : 1) * 262144;
        const int r = t >> 4, q4 = (t & 15) * 4;
        #pragma unroll
        for (int it = 0; it < 4; ++it) {
            const int row = it * 16 + r;
            float4 v = *(const float4*)(W + (size_t)(c0 + row) * 512 + n0 + q4);
            if (z == 3) {
                ushort4 h4 = { f2h(v.x), f2h(v.y), f2h(v.z), f2h(v.w) };
                *(ushort4*)(D + (size_t)(c0 + row) * 512 + n0 + q4) = h4;
            } else {
                tile[row][q4 + 0] = v.x; tile[row][q4 + 1] = v.y;
                tile[row][q4 + 2] = v.z; tile[row][q4 + 3] = v.w;
            }
        }
        __syncthreads();
        if (z == 3) return;
        #pragma unroll
        for (int it = 0; it < 4; ++it) {
            const int nrow = it * 16 + r;
            ushort4 h4;
            h4.x = f2h(tile[q4 + 0][nrow]);
            h4.y = f2h(tile[q4 + 1][nrow]);
            h4.z = f2h(tile[q4 + 2][nrow]);
            h4.w = f2h(tile[q4 + 3][nrow]);
            *(ushort4*)(D + (size_t)(n0 + nrow) * 512 + c0 + q4) = h4;
        }
        return;
    }
    const int flat = blockIdx.y * 8 + blockIdx.x;
    if (flat < 8) {               // finalize stats
        #pragma unroll
        for (int h = 0; h < 2; ++h) {
            const int c = flat * 512 + h * 256 + t;
            const float S = part_s[c], SS = part_ss[c];
            const float mean = S * (1.f / N_SP);
            const float var = (SS - S * mean) * (1.f / (N_SP - 1));
            mu_a[c] = mean;
            rs_a[c] = rsqrtf(var + 1e-5f);
        }
    } else if (flat < 10) {       // w_u[d] = sum_o b_c1[o] W_s1[o][d]
        const int d = (flat - 8) * 256 + t;
        float acc = 0.f;
        for (int o = 0; o < 512; ++o) acc += b_c1[o] * W_s1[(size_t)o * 512 + d];
        w_u[d] = acc;
    } else if (flat < 42) {       // bfold0[o] = sum_c W_csc[o][c] b_s2[c] + b_csc[o]
        const int w4 = t >> 6, l = t & 63;
        #pragma unroll
        for (int q = 0; q < 4; ++q) {
            const int o = (flat - 10) * 16 + w4 * 4 + q;
            const float4 w0 = *(const float4*)(W_csc + (size_t)o * 512 + l * 8);
            const float4 w1 = *(const float4*)(W_csc + (size_t)o * 512 + l * 8 + 4);
            const float4 b0 = *(const float4*)(b_s2 + l * 8);
            const float4 b1 = *(const float4*)(b_s2 + l * 8 + 4);
            float acc = w0.x * b0.x + w0.y * b0.y + w0.z * b0.z + w0.w * b0.w
                      + w1.x * b1.x + w1.y * b1.y + w1.z * b1.z + w1.w * b1.w;
            acc = wave_reduce_sum(acc);
            if (l == 0) bfold0[o] = acc + b_csc[o];
        }
    }
}

// ---- prep2: make_scaled + bias2 + u_big, one launch (grid 2304) ----
__global__ __launch_bounds__(256) void prep2(
        const u16* __restrict__ WqT16, const u16* __restrict__ Wf16,
        const u16* __restrict__ xs,
        const float* __restrict__ mu_a, const float* __restrict__ rs_a,
        const float* __restrict__ bfold0, const float* __restrict__ w_u,
        u16* __restrict__ Wq_z, u16* __restrict__ Wf_z,
        float* __restrict__ bq, float* __restrict__ bh, float* __restrict__ u_) {
    const int id = blockIdx.x, t = threadIdx.x;
    if (id < 1024) {              // make_scaled
        const int y = id >> 9;
        const size_t e = ((size_t)(id & 511) * 256 + t) * 8;
        const int z = (int)(e >> 18), rem = (int)(e & 262143);
        const int d = rem >> 9, a0 = rem & 511;
        u16 v[8];
        if (y == 0) {
            *(uint4*)v = *(const uint4*)(WqT16 + rem);
            const float rd = rs_a[(4 + z) * 512 + d];
            const float* rc = rs_a + z * 512 + a0;
            #pragma unroll
            for (int i = 0; i < 8; ++i) v[i] = f2h(h2f(v[i]) * rc[i] * rd);
            *(uint4*)(Wq_z + e) = *(const uint4*)v;
        } else {
            *(uint4*)v = *(const uint4*)(Wf16 + rem);
            const float* rk = rs_a + (4 + z) * 512 + a0;
            #pragma unroll
            for (int i = 0; i < 8; ++i) v[i] = f2h(h2f(v[i]) * rk[i]);
            *(uint4*)(Wf_z + e) = *(const uint4*)v;
        }
    } else if (id < 2048) {       // bias2
        const int w = t >> 6, l = t & 63;
        const int oid = (id - 1024) * 4 + w;
        const int kind = oid >> 11;
        const int z = (oid >> 9) & 3, d = oid & 511;
        const u16* row = (kind == 0 ? WqT16 : Wf16) + (size_t)d * 512;
        const int sb = (kind == 0 ? z : 4 + z) * 512;
        float acc = 0.f;
        #pragma unroll
        for (int i = 0; i < 8; ++i) {
            const int a = l * 8 + i;
            acc += h2f(row[a]) * mu_a[sb + a] * rs_a[sb + a];
        }
        acc = wave_reduce_sum(acc);
        if (l == 0) {
            if (kind == 0) bq[z * 512 + d] = -acc * rs_a[(4 + z) * 512 + d];
            else           bh[z * 512 + d] = bfold0[d] - acc;
        }
    } else {                      // u_big
        const int id2 = id - 2048;                 // 0..255
        const int b = id2 >> 6, xblk = id2 & 63;
        const int w = t >> 6, l = t & 63;
        float4 u0 = *(const float4*)(w_u + l * 8);
        float4 u1 = *(const float4*)(w_u + l * 8 + 4);
        const float4 r0 = *(const float4*)(rs_a + (4 + b) * 512 + l * 8);
        const float4 r1 = *(const float4*)(rs_a + (4 + b) * 512 + l * 8 + 4);
        u0.x *= r0.x; u0.y *= r0.y; u0.z *= r0.z; u0.w *= r0.w;
        u1.x *= r1.x; u1.y *= r1.y; u1.z *= r1.z; u1.w *= r1.w;
        #pragma unroll
        for (int jj = 0; jj < 16; ++jj) {
            const int j = xblk * 64 + w * 16 + jj;
            const u16* row = xs + ((size_t)b * N_SP + j) * C_CH + l * 8;
            f16x8 x = *(const f16x8*)row;
            float acc = (float)x[0] * u0.x + (float)x[1] * u0.y + (float)x[2] * u0.z + (float)x[3] * u0.w
                      + (float)x[4] * u1.x + (float)x[5] * u1.y + (float)x[6] * u1.z + (float)x[7] * u1.w;
            acc = wave_reduce_sum(acc);
            if (l == 0) u_[(size_t)b * N_SP + j] = acc;
        }
    }
}

// ---------------- legacy 4-wave GEMM (32x32x16): kept only for the small 512^3 weight GEMM ----
enum { OUT_F32 = 0, OUT_F16 = 1 };

template<int OUTMODE, bool TABB, bool TABD, int MI, int MJ>
__global__ __launch_bounds__(256) void gemm_bt(
    const u16* __restrict__ A, const u16* __restrict__ B, PtrTab tab,
    float* __restrict__ Df, u16* __restrict__ Dh,
    const float* __restrict__ bias_m, const float* __restrict__ bias_n,
    const float* __restrict__ res,
    int M, int N, int K, int lda, int ldb, int ldd,
    size_t sA, size_t sB, size_t sD, size_t sR, int sBm, int sBn)
{
    constexpr int TM = MI * 64, TN = MJ * 64, BK = 64;
    constexpr int AITS = (TM * BK) / (256 * 8);
    constexpr int BITS = (TN * BK) / (256 * 8);
    __shared__ u16 smem[(TM + TN) * BK];
    u16* As = smem;
    u16* Bs = smem + TM * BK;

    const int t = threadIdx.x;
    const int l = t & 63, w = t >> 6;
    const int m0 = blockIdx.y * TM, n0 = blockIdx.x * TN;
    const size_t zb = blockIdx.z;
    const u16* pA = A + zb * sA + (size_t)m0 * lda;
    const u16* pB = (TABB ? tab.p[zb] : B + zb * sB) + (size_t)n0 * ldb;

    const int wr = (w & 1) * (MI * 32), wc = (w >> 1) * (MJ * 32);

    f32x16 acc[MI][MJ] = {};

    for (int k0 = 0; k0 < K; k0 += BK) {
        #pragma unroll
        for (int it = 0; it < AITS; ++it) {
            const int L = it * 256 + t;
            const int row = L >> 3, c = L & 7;
            const int sc = (c ^ (row & 7)) * 8;
            async_cp16(pA + (size_t)row * lda + k0 + sc, As + L * 8);
        }
        #pragma unroll
        for (int it = 0; it < BITS; ++it) {
            const int L = it * 256 + t;
            const int row = L >> 3, c = L & 7;
            const int sc = (c ^ (row & 7)) * 8;
            async_cp16(pB + (size_t)row * ldb + k0 + sc, Bs + L * 8);
        }
        __syncthreads();
        #pragma unroll
        for (int kk = 0; kk < 4; ++kk) {
            f16x8 af[MI], bf[MJ];
            #pragma unroll
            for (int i = 0; i < MI; ++i) {
                const int row = wr + i * 32 + (l & 31);
                const int ch = ((kk * 2 + (l >> 5)) ^ (row & 7)) * 8;
                af[i] = *(const f16x8*)(As + row * BK + ch);
            }
            #pragma unroll
            for (int j = 0; j < MJ; ++j) {
                const int row = wc + j * 32 + (l & 31);
                const int ch = ((kk * 2 + (l >> 5)) ^ (row & 7)) * 8;
                bf[j] = *(const f16x8*)(Bs + row * BK + ch);
            }
            #pragma unroll
            for (int i = 0; i < MI; ++i)
                #pragma unroll
                for (int j = 0; j < MJ; ++j)
                    acc[i][j] = __builtin_amdgcn_mfma_f32_32x32x16_f16(af[i], bf[j], acc[i][j], 0, 0, 0);
        }
        __syncthreads();
    }

    const int cl = l & 31, rh = (l >> 5) * 4;
    u16* pDh = (OUTMODE == OUT_F16) ? (TABD ? tab.p[zb] : Dh + zb * sD) : nullptr;
    float* pDf = (OUTMODE == OUT_F32) ? (Df + zb * sD) : nullptr;
    #pragma unroll
    for (int i = 0; i < MI; ++i) {
        #pragma unroll
        for (int j = 0; j < MJ; ++j) {
            const int nn = n0 + wc + j * 32 + cl;
            const float bn = bias_n ? bias_n[(size_t)sBn * zb + nn] : 0.f;
            #pragma unroll
            for (int reg = 0; reg < 16; ++reg) {
                const int ml = (reg & 3) + 8 * (reg >> 2) + rh;
                const int mm = m0 + wr + i * 32 + ml;
                float v = acc[i][j][reg] + bn;
                if (bias_m) v += bias_m[(size_t)sBm * zb + mm];
                const size_t off = (size_t)mm * ldd + nn;
                if (OUTMODE == OUT_F32) {
                    if (res) v += res[zb * sR + off];
                    pDf[off] = v;
                } else {
                    pDh[off] = f2h(v);
                }
            }
        }
    }
}

// ======== 8-wave 4-phase GEMM, 16x16x32 frags + FULL 3-bit XOR swizzle (2-way = free) ========
// Bank math (the round-5 fix): row stride = BK*2B = 128B so bank = (chunk*4) mod 32 — rows
// contribute nothing. 16x16x32 A/B frags span 16 rows per quarter-wave; reading chunk
// ch = (kk*4 + (l>>4)) ^ (row&7) gives 8 distinct chunks x 2 lanes = 2-way (free, m136).
// (r0/r1 used this XOR on 32-row frags -> 4-way; r3 used 1-bit XOR on 16-row frags -> 8-way.)
// Staging: global_load_lds, linear LDS dest, pre-swizzled SOURCE chunk (c ^ (row&7)) — the
// proven r0/r1 pattern (involution; rule #21). No reg-staging (r4's spill disaster).
// Tour: p0:A0xB0 (read A0,B0), p1:A1xB0 (read A1), p2:A1xB1 (read B1), p3:A0xB1 (all held)
// — 12 reads/wave/tile. Stage next tile: Ah0@p0, Ah1@p1, Bh0@p2, Bh1@p3.
// Counted vmwaits (queue order [Ah0,Ah1,Bh0,Bh1] per tile): end-p1 vmwait<2*LA> drains
// Bh1(cur) (issued 2.5 phases earlier); end-p3 vmwait<LB> drains Ah0,Ah1,Bh0(next).
// Each vmwait precedes a barrier -> per-wave guarantee becomes block-wide (symmetric loads).
template<int OUTMODE, bool TABB, bool TABD, int BM>
__global__ __launch_bounds__(512, 2) void gemm_f(
    const u16* __restrict__ A, const u16* __restrict__ B, PtrTab tab,
    float* __restrict__ Df, u16* __restrict__ Dh,
    const float* __restrict__ bias_m, const float* __restrict__ bias_n,
    const float* __restrict__ res,
    int K, int lda, int ldb, int ldd,
    size_t sA, size_t sB, size_t sD, size_t sR, int sBm, int sBn)
{
    constexpr int BN = 256, BK = 64;
    constexpr int HM = BM / 2;            // A-half rows
    constexpr int MF = BM / 64;           // 16-row m-frags per half per wave
    constexpr int LA = BM / 128;          // gload insts/thread per A-half
    constexpr int LB = 2;                 // gload insts/thread per B-half
    constexpr int LDSH = (BM + BN) * BK;  // u16 per buffer
    __shared__ u16 smem[2 * LDSH];

    const int t = threadIdx.x;
    const int l = t & 63, w = t >> 6;
    const int m0 = blockIdx.y * BM, n0 = blockIdx.x * BN;
    const size_t zb = blockIdx.z;
    const u16* pA = A + zb * sA + (size_t)m0 * lda;
    const u16* pB = (TABB ? tab.p[zb] : B + zb * sB) + (size_t)n0 * ldb;

    const int wr = (w & 1) * (HM / 2);    // wave row offset within an A-half
    const int wc = (w >> 1) * 32;         // wave col offset within a B-half (128)

    f32x4 acc[2 * MF][4] = {};

    auto stageA = [&](int buf, int k0, int half) {
        u16* dst = smem + buf * LDSH;
        #pragma unroll
        for (int it = 0; it < LA; ++it) {
            const int L = it * 512 + t;
            const int row = half * HM + (L >> 3), c = L & 7;
            const int sc = (c ^ (row & 7)) * 8;   // pre-swizzled SOURCE, linear LDS dest
            async_cp16(pA + (size_t)row * lda + k0 + sc, dst + row * BK + c * 8);
        }
    };
    auto stageB = [&](int buf, int k0, int half) {
        u16* dst = smem + buf * LDSH + BM * BK;
        #pragma unroll
        for (int it = 0; it < LB; ++it) {
            const int L = it * 512 + t;
            const int row = half * 128 + (L >> 3), c = L & 7;
            const int sc = (c ^ (row & 7)) * 8;
            async_cp16(pB + (size_t)row * ldb + k0 + sc, dst + row * BK + c * 8);
        }
    };
    auto rdA = [&](const u16* As, int qi, int mf, int kk) -> f16x8 {
        const int row = qi * HM + wr + mf * 16 + (l & 15);
        const int ch = (kk * 4 + (l >> 4)) ^ (row & 7);   // FULL 3-bit XOR -> 2-way free
        return *(const f16x8*)(As + row * BK + ch * 8);
    };
    auto rdB = [&](const u16* Bs, int qj, int nf, int kk) -> f16x8 {
        const int row = qj * 128 + wc + nf * 16 + (l & 15);
        const int ch = (kk * 4 + (l >> 4)) ^ (row & 7);
        return *(const f16x8*)(Bs + row * BK + ch * 8);
    };

    f16x8 af[2][MF][2];   // af[0]=A0 (live p0..p3), af[1]=A1 (live p1..p2)
    f16x8 bf[2][2];       // B0 (p0..p1) then overwritten by B1 (p2..p3)

    const int NT = K / BK;
    // prologue: tile 0 staged in steady-state queue order; leave Bh1 in flight
    stageA(0, 0, 0); stageA(0, 0, 1); stageB(0, 0, 0); stageB(0, 0, 1);
    vmwait<LB>();
    bar();

    for (int tl = 0; tl < NT; ++tl) {
        const int cur = tl & 1, nxt = cur ^ 1;
        const u16* As = smem + cur * LDSH;
        const u16* Bs = As + BM * BK;
        const int k1 = (tl + 1) * BK;
        const bool pf = (tl + 1 < NT);

        // ---- phase 0: A0 x B0 ----
        #pragma unroll
        for (int mf = 0; mf < MF; ++mf) { af[0][mf][0] = rdA(As, 0, mf, 0); af[0][mf][1] = rdA(As, 0, mf, 1); }
        #pragma unroll
        for (int nf = 0; nf < 2; ++nf) { bf[nf][0] = rdB(Bs, 0, nf, 0); bf[nf][1] = rdB(Bs, 0, nf, 1); }
        if (pf) stageA(nxt, k1, 0);
        lgkm0();
        __builtin_amdgcn_s_setprio(1);
        #pragma unroll
        for (int mf = 0; mf < MF; ++mf)
            #pragma unroll
            for (int nf = 0; nf < 2; ++nf) {
                acc[mf][nf] = __builtin_amdgcn_mfma_f32_16x16x32_f16(af[0][mf][0], bf[nf][0], acc[mf][nf], 0, 0, 0);
                acc[mf][nf] = __builtin_amdgcn_mfma_f32_16x16x32_f16(af[0][mf][1], bf[nf][1], acc[mf][nf], 0, 0, 0);
            }
        __builtin_amdgcn_s_setprio(0);
        bar();

        // ---- phase 1: A1 x B0 (B held) ----
        #pragma unroll
        for (int mf = 0; mf < MF; ++mf) { af[1][mf][0] = rdA(As, 1, mf, 0); af[1][mf][1] = rdA(As, 1, mf, 1); }
        if (pf) stageA(nxt, k1, 1);
        lgkm0();
        __builtin_amdgcn_s_setprio(1);
        #pragma unroll
        for (int mf = 0; mf < MF; ++mf)
            #pragma unroll
            for (int nf = 0; nf < 2; ++nf) {
                acc[MF + mf][nf] = __builtin_amdgcn_mfma_f32_16x16x32_f16(af[1][mf][0], bf[nf][0], acc[MF + mf][nf], 0, 0, 0);
                acc[MF + mf][nf] = __builtin_amdgcn_mfma_f32_16x16x32_f16(af[1][mf][1], bf[nf][1], acc[MF + mf][nf], 0, 0, 0);
            }
        __builtin_amdgcn_s_setprio(0);
        if (pf) vmwait<2 * LA>(); else vmwait<0>();   // Bh1(cur) landed; Ah0/Ah1(next) in flight
        bar();

        // ---- phase 2: A1 (held) x B1 ----
        #pragma unroll
        for (int nf = 0; nf < 2; ++nf) { bf[nf][0] = rdB(Bs, 1, nf, 0); bf[nf][1] = rdB(Bs, 1, nf, 1); }
        if (pf) stageB(nxt, k1, 0);
        lgkm0();
        __builtin_amdgcn_s_setprio(1);
        #pragma unroll
        for (int mf = 0; mf < MF; ++mf)
            #pragma unroll
            for (int nf = 0; nf < 2; ++nf) {
                acc[MF + mf][2 + nf] = __builtin_amdgcn_mfma_f32_16x16x32_f16(af[1][mf][0], bf[nf][0], acc[MF + mf][2 + nf], 0, 0, 0);
                acc[MF + mf][2 + nf] = __builtin_amdgcn_mfma_f32_16x16x32_f16(af[1][mf][1], bf[nf][1], acc[MF + mf][2 + nf], 0, 0, 0);
            }
        __builtin_amdgcn_s_setprio(0);
        bar();

        // ---- phase 3: A0 (held) x B1 (held) — no LDS reads ----
        if (pf) stageB(nxt, k1, 1);
        __builtin_amdgcn_s_setprio(1);
        #pragma unroll
        for (int mf = 0; mf < MF; ++mf)
            #pragma unroll
            for (int nf = 0; nf < 2; ++nf) {
                acc[mf][2 + nf] = __builtin_amdgcn_mfma_f32_16x16x32_f16(af[0][mf][0], bf[nf][0], acc[mf][2 + nf], 0, 0, 0);
                acc[mf][2 + nf] = __builtin_amdgcn_mfma_f32_16x16x32_f16(af[0][mf][1], bf[nf][1], acc[mf][2 + nf], 0, 0, 0);
            }
        __builtin_amdgcn_s_setprio(0);
        if (pf) vmwait<LB>();                         // Ah0,Ah1,Bh0(next) landed for next p0/p1
        bar();
    }

    // C/D (16x16): col = lane&15, row = (lane>>4)*4 + reg   (validated r3)
    const int cl = l & 15, rh = (l >> 4) * 4;
    u16* pDh = (OUTMODE == OUT_F16) ? (TABD ? tab.p[zb] : Dh + zb * sD) : nullptr;
    float* pDf = (OUTMODE == OUT_F32) ? (Df + zb * sD) : nullptr;
    #pragma unroll
    for (int qi = 0; qi < 2; ++qi) {
        #pragma unroll
        for (int qj = 0; qj < 2; ++qj) {
            #pragma unroll
            for (int mf = 0; mf < MF; ++mf) {
                #pragma unroll
                for (int nf = 0; nf < 2; ++nf) {
                    const int nn = n0 + qj * 128 + wc + nf * 16 + cl;
                    const float bn = bias_n ? bias_n[(size_t)sBn * zb + nn] : 0.f;
                    const f32x4 a4 = acc[qi * MF + mf][qj * 2 + nf];
                    #pragma unroll
                    for (int reg = 0; reg < 4; ++reg) {
                        const int mm = m0 + qi * HM + wr + mf * 16 + rh + reg;
                        float v = a4[reg] + bn;
                        if (bias_m) v += bias_m[(size_t)sBm * zb + mm];
                        const size_t off = (size_t)mm * ldd + nn;
                        if (OUTMODE == OUT_F32) {
                            if (res) v += res[zb * sR + off];
                            pDf[off] = v;
                        } else {
                            pDh[off] = f2h(v);
                        }
                    }
                }
            }
        }
    }
}

// ---------------- softmax row-wise, fp16 in-place ----------------
__global__ __launch_bounds__(256) void softmax_kernel(PtrTab tab) {
    u16* row = tab.p[blockIdx.y] + (size_t)blockIdx.x * N_SP;
    const int t = threadIdx.x;
    u16 raw[16];
    *(uint4*)(raw + 0) = *(const uint4*)(row + t * 16);
    *(uint4*)(raw + 8) = *(const uint4*)(row + t * 16 + 8);
    float v[16];
    float mx = -1e30f;
    #pragma unroll
    for (int i = 0; i < 16; ++i) { v[i] = h2f(raw[i]); mx = fmaxf(mx, v[i]); }
    mx = wave_reduce_max(mx);
    __shared__ float red[4];
    const int wave = t >> 6;
    if ((t & 63) == 0) red[wave] = mx;
    __syncthreads();
    mx = fmaxf(fmaxf(red[0], red[1]), fmaxf(red[2], red[3]));
    float sum = 0.f;
    #pragma unroll
    for (int i = 0; i < 16; ++i) { v[i] = __expf(v[i] - mx); sum += v[i]; }
    sum = wave_reduce_sum(sum);
    __syncthreads();
    if ((t & 63) == 0) red[wave] = sum;
    __syncthreads();
    const float inv = 1.f / (red[0] + red[1] + red[2] + red[3]);
    #pragma unroll
    for (int i = 0; i < 16; ++i) raw[i] = f2h(v[i] * inv);
    *(uint4*)(row + t * 16)     = *(const uint4*)(raw + 0);
    *(uint4*)(row + t * 16 + 8) = *(const uint4*)(raw + 8);
}

extern "C" void kernel_launch(void* const* d_in, const int* in_sizes, int n_in,
                              void* d_out, int out_size, void* d_ws, size_t ws_size,
                              hipStream_t stream) {
    const float* f_c   = (const float*)d_in[0];
    const float* f_s   = (const float*)d_in[1];
    const float* W_c1  = (const float*)d_in[2];
    const float* b_c1  = (const float*)d_in[3];
    const float* W_s1  = (const float*)d_in[4];
    const float* b_s1  = (const float*)d_in[5]; (void)b_s1;   // softmax-invariant, dropped
    const float* W_s2  = (const float*)d_in[6];
    const float* b_s2  = (const float*)d_in[7];
    const float* W_csc = (const float*)d_in[8];
    const float* b_csc = (const float*)d_in[9];

    const size_t PB = (size_t)N_SP * C_CH;      // 2M elems per batch plane
    const size_t M1 = 1024 * 1024;

    u16* ws   = (u16*)d_ws;
    u16* Xs   = ws;                 // raw fp16 [b][j][c]   0..8M
    u16* q_   = ws + 8 * M1;        // q'[b][i][d]          8..16M
    u16* hc   = ws + 16 * M1;       // hc[b][o][j]          16..24M
    u16* Xc   = ws + 24 * M1;       // raw fp16 (dead after q'-conv; S3 aliases)
    u16* S3   = ws + 24 * M1;
    u16* S0   = ws + 40 * M1;
    u16* S1   = ws + 56 * M1;
    u16* S2   = ws + 72 * M1;
    u16* Wbase= ws + 88 * M1;       // 6 x 262144: Ws1T, Wcs16, Wc1T, Ws2T, WqT16, Wf16
    u16* WqT16= Wbase + 4 * 262144;
    u16* Wf16 = Wbase + 5 * 262144;
    u16* Wq_z = Wbase + 6 * 262144; // 4 x 256K
    u16* Wf_z = Wq_z + 1048576;     // 4 x 256K
    float* f32b = (float*)(ws + 92 * M1);
    float* part_s  = f32b;          // 4096
    float* part_ss = f32b + 4096;
    float* mu_a    = f32b + 8192;
    float* rs_a    = f32b + 12288;
    float* w_u     = f32b + 16384;  // 512
    float* bfold0  = f32b + 16896;  // 512
    float* bq      = f32b + 17408;  // 2048
    float* bh      = f32b + 19456;  // 2048
    float* u_      = f32b + 21504;  // 4*4096

    PtrTab Stab; Stab.p[0] = S0; Stab.p[1] = S1; Stab.p[2] = S2; Stab.p[3] = S3;
    PtrTab tab0 = Stab;

    hipMemsetAsync(part_s, 0, 2 * 4096 * sizeof(float), stream);

    transpose_cast_stats<<<dim3(64, 8, 8), 256, 0, stream>>>(f_c, f_s, Xc, Xs, part_s, part_ss);

    // weight transforms + stats finalize + small gemvs, one launch
    prep1<<<dim3(8, 8, 5), 256, 0, stream>>>(W_c1, W_s1, W_s2, W_csc, b_c1, b_s2, b_csc,
                                             Wbase, part_s, part_ss, mu_a, rs_a, w_u, bfold0);

    // WqT[d][a] = sum_o Ws1T[d][o] Wc1T[a][o]; Wfold[o][k] = sum_c Wcs16[o][c] Ws2T[k][c]
    gemm_bt<OUT_F16, false, false, 2, 2><<<dim3(4, 4, 2), 256, 0, stream>>>(
        Wbase, Wbase + 2 * 262144, tab0, nullptr, WqT16, nullptr, nullptr, nullptr,
        512, 512, 512, 512, 512, 512, 262144, 262144, 262144, 0, 0, 0);

    // per-batch scaled weights + folded biases + u vector, one launch
    prep2<<<2304, 256, 0, stream>>>(WqT16, Wf16, Xs, mu_a, rs_a, bfold0, w_u,
                                    Wq_z, Wf_z, bq, bh, u_);

    // q'[b][i][d] = sum_a Xc_raw[b][i][a] Wq_z[b][d][a] + bq[b][d]
    gemm_f<OUT_F16, false, false, 128><<<dim3(2, 32, B_SZ), 512, 0, stream>>>(
        Xc, Wq_z, tab0, nullptr, q_, nullptr, bq, nullptr,
        C_CH, C_CH, C_CH, C_CH, PB, 262144, PB, 0, 0, 512);
    // hc[b][o][j] = sum_k Wf_z[b][o][k] Xs_raw[b][j][k] + bh[b][o]
    gemm_f<OUT_F16, false, false, 128><<<dim3(16, 4, B_SZ), 512, 0, stream>>>(
        Wf_z, Xs, tab0, nullptr, hc, bh, nullptr, nullptr,
        C_CH, C_CH, C_CH, N_SP, 262144, PB, PB, 0, 512, 0);

    // S_b[i][j] = sum_d q'[i][d] Xs_raw[j][d] + u[b][j]
    gemm_f<OUT_F16, false, true, 128><<<dim3(16, 32, B_SZ), 512, 0, stream>>>(
        q_, Xs, Stab, nullptr, nullptr, nullptr, u_, nullptr,
        C_CH, C_CH, C_CH, N_SP, PB, PB, 0, 0, 0, N_SP);

    softmax_kernel<<<dim3(N_SP, B_SZ), 256, 0, stream>>>(Stab);

    // out[b][o][i] = sum_j hc[o][j] P[i][j] + f_c
    gemm_f<OUT_F32, true, false, 128><<<dim3(16, 4, B_SZ), 512, 0, stream>>>(
        hc, nullptr, Stab, (float*)d_out, nullptr, nullptr, nullptr, f_c,
        N_SP, N_SP, N_SP, N_SP, PB, 0, PB, PB, 0, 0);
}

// Round 8
// 423.504 us; speedup vs baseline: 1.5394x; 1.0590x over previous
//
#include <hip/hip_runtime.h>

typedef unsigned short u16;
typedef __attribute__((ext_vector_type(8))) _Float16 f16x8;
typedef __attribute__((ext_vector_type(4))) float f32x4;
typedef __attribute__((ext_vector_type(16))) float f32x16;

#define N_SP 4096
#define C_CH 512
#define B_SZ 4

struct PtrTab { u16* p[4]; };

__device__ __forceinline__ u16 f2h(float f) {
    union { _Float16 h; u16 u; } x; x.h = (_Float16)f; return x.u;
}
__device__ __forceinline__ float h2f(u16 u) {
    union { u16 u; _Float16 h; } x; x.u = u; return (float)x.h;
}
__device__ __forceinline__ void async_cp16(const void* g, void* l) {
    __builtin_amdgcn_global_load_lds((const __attribute__((address_space(1))) unsigned*)g,
                                     (__attribute__((address_space(3))) unsigned*)l, 16, 0, 0);
}
__device__ __forceinline__ float wave_reduce_sum(float v) {
    #pragma unroll
    for (int off = 32; off; off >>= 1) v += __shfl_xor(v, off, 64);
    return v;
}
__device__ __forceinline__ float wave_reduce_max(float v) {
    #pragma unroll
    for (int off = 32; off; off >>= 1) v = fmaxf(v, __shfl_xor(v, off, 64));
    return v;
}
// raw barrier: hardware barrier + compiler memory fence, NO vmcnt drain
__device__ __forceinline__ void bar() { asm volatile("s_barrier" ::: "memory"); }
template<int N> __device__ __forceinline__ void vmwait() {
    if constexpr (N == 0)  asm volatile("s_waitcnt vmcnt(0)" ::: "memory");
    else if constexpr (N == 2)  asm volatile("s_waitcnt vmcnt(2)" ::: "memory");
    else if constexpr (N == 4)  asm volatile("s_waitcnt vmcnt(4)" ::: "memory");
    else if constexpr (N == 6)  asm volatile("s_waitcnt vmcnt(6)" ::: "memory");
    else if constexpr (N == 8)  asm volatile("s_waitcnt vmcnt(8)" ::: "memory");
}
__device__ __forceinline__ void lgkm0() {
    asm volatile("s_waitcnt lgkmcnt(0)" ::: "memory");
    __builtin_amdgcn_sched_barrier(0);
}

// ---- transpose+cast raw x to fp16 [b][n][c], accumulate per-channel partial stats ----
__global__ __launch_bounds__(256) void transpose_cast_stats(
        const float* __restrict__ fc, const float* __restrict__ fs,
        u16* __restrict__ xc, u16* __restrict__ xs,
        float* __restrict__ part_s, float* __restrict__ part_ss) {
    __shared__ float tile[64][65];
    const int t = threadIdx.x;
    const int n0 = blockIdx.x * 64, c0 = blockIdx.y * 64;
    const int z = blockIdx.z;                      // (which<<2)|b
    const int b = z & 3, which = z >> 2;
    const float* src = which ? fs : fc;
    u16* dst = which ? xs : xc;
    const int r = t >> 4, q4 = (t & 15) * 4;
    #pragma unroll
    for (int it = 0; it < 4; ++it) {
        const int row = it * 16 + r;
        float4 v = *(const float4*)(src + ((size_t)b * C_CH + c0 + row) * N_SP + n0 + q4);
        tile[row][q4 + 0] = v.x; tile[row][q4 + 1] = v.y;
        tile[row][q4 + 2] = v.z; tile[row][q4 + 3] = v.w;
    }
    __syncthreads();
    {
        const int cr = t >> 2, q = t & 3;
        float s = 0.f, ss = 0.f;
        #pragma unroll
        for (int i = 0; i < 16; ++i) {
            float a = tile[cr][q * 16 + i];
            s += a; ss += a * a;
        }
        s += __shfl_xor(s, 1, 64);  s += __shfl_xor(s, 2, 64);
        ss += __shfl_xor(ss, 1, 64); ss += __shfl_xor(ss, 2, 64);
        if (q == 0) {
            atomicAdd(&part_s[z * 512 + c0 + cr], s);
            atomicAdd(&part_ss[z * 512 + c0 + cr], ss);
        }
    }
    #pragma unroll
    for (int it = 0; it < 4; ++it) {
        const int nrow = it * 16 + r;
        ushort4 h4;
        h4.x = f2h(tile[q4 + 0][nrow]);
        h4.y = f2h(tile[q4 + 1][nrow]);
        h4.z = f2h(tile[q4 + 2][nrow]);
        h4.w = f2h(tile[q4 + 3][nrow]);
        *(ushort4*)(dst + ((size_t)b * N_SP + n0 + nrow) * C_CH + c0 + q4) = h4;
    }
}

// ---- prep1: weight transpose/cast + finalize stats + wu gemv + bfold gemv ----
// Wbase slots (each 262144 u16): 0 Ws1T, 1 Wcs16, 2 Wc1T, 3 Ws2T, 4 WqT16, 5 Wf16
__global__ __launch_bounds__(256) void prep1(
        const float* __restrict__ W_c1, const float* __restrict__ W_s1,
        const float* __restrict__ W_s2, const float* __restrict__ W_csc,
        const float* __restrict__ b_c1, const float* __restrict__ b_s2,
        const float* __restrict__ b_csc,
        u16* __restrict__ Wbase,
        const float* __restrict__ part_s, const float* __restrict__ part_ss,
        float* __restrict__ mu_a, float* __restrict__ rs_a,
        float* __restrict__ w_u, float* __restrict__ bfold0) {
    __shared__ float tile[64][65];
    const int t = threadIdx.x, z = blockIdx.z;
    if (z < 4) {
        const int n0 = blockIdx.x * 64, c0 = blockIdx.y * 64;
        const float* W = (z == 0) ? W_c1 : (z == 1) ? W_s1 : (z == 2) ? W_s2 : W_csc;
        u16* D = Wbase + ((z == 0) ? 2 : (z == 1) ? 0 : (z == 2) ? 3 : 1) * 262144;
        const int r = t >> 4, q4 = (t & 15) * 4;
        #pragma unroll
        for (int it = 0; it < 4; ++it) {
            const int row = it * 16 + r;
            float4 v = *(const float4*)(W + (size_t)(c0 + row) * 512 + n0 + q4);
            if (z == 3) {
                ushort4 h4 = { f2h(v.x), f2h(v.y), f2h(v.z), f2h(v.w) };
                *(ushort4*)(D + (size_t)(c0 + row) * 512 + n0 + q4) = h4;
            } else {
                tile[row][q4 + 0] = v.x; tile[row][q4 + 1] = v.y;
                tile[row][q4 + 2] = v.z; tile[row][q4 + 3] = v.w;
            }
        }
        __syncthreads();
        if (z == 3) return;
        #pragma unroll
        for (int it = 0; it < 4; ++it) {
            const int nrow = it * 16 + r;
            ushort4 h4;
            h4.x = f2h(tile[q4 + 0][nrow]);
            h4.y = f2h(tile[q4 + 1][nrow]);
            h4.z = f2h(tile[q4 + 2][nrow]);
            h4.w = f2h(tile[q4 + 3][nrow]);
            *(ushort4*)(D + (size_t)(n0 + nrow) * 512 + c0 + q4) = h4;
        }
        return;
    }
    const int flat = blockIdx.y * 8 + blockIdx.x;
    if (flat < 8) {               // finalize stats
        #pragma unroll
        for (int h = 0; h < 2; ++h) {
            const int c = flat * 512 + h * 256 + t;
            const float S = part_s[c], SS = part_ss[c];
            const float mean = S * (1.f / N_SP);
            const float var = (SS - S * mean) * (1.f / (N_SP - 1));
            mu_a[c] = mean;
            rs_a[c] = rsqrtf(var + 1e-5f);
        }
    } else if (flat < 10) {       // w_u[d] = sum_o b_c1[o] W_s1[o][d]
        const int d = (flat - 8) * 256 + t;
        float acc = 0.f;
        for (int o = 0; o < 512; ++o) acc += b_c1[o] * W_s1[(size_t)o * 512 + d];
        w_u[d] = acc;
    } else if (flat < 42) {       // bfold0[o] = sum_c W_csc[o][c] b_s2[c] + b_csc[o]
        const int w4 = t >> 6, l = t & 63;
        #pragma unroll
        for (int q = 0; q < 4; ++q) {
            const int o = (flat - 10) * 16 + w4 * 4 + q;
            const float4 w0 = *(const float4*)(W_csc + (size_t)o * 512 + l * 8);
            const float4 w1 = *(const float4*)(W_csc + (size_t)o * 512 + l * 8 + 4);
            const float4 b0 = *(const float4*)(b_s2 + l * 8);
            const float4 b1 = *(const float4*)(b_s2 + l * 8 + 4);
            float acc = w0.x * b0.x + w0.y * b0.y + w0.z * b0.z + w0.w * b0.w
                      + w1.x * b1.x + w1.y * b1.y + w1.z * b1.z + w1.w * b1.w;
            acc = wave_reduce_sum(acc);
            if (l == 0) bfold0[o] = acc + b_csc[o];
        }
    }
}

// ---- prep2: make_scaled + bias2 + u_big, one launch (grid 2304) ----
__global__ __launch_bounds__(256) void prep2(
        const u16* __restrict__ WqT16, const u16* __restrict__ Wf16,
        const u16* __restrict__ xs,
        const float* __restrict__ mu_a, const float* __restrict__ rs_a,
        const float* __restrict__ bfold0, const float* __restrict__ w_u,
        u16* __restrict__ Wq_z, u16* __restrict__ Wf_z,
        float* __restrict__ bq, float* __restrict__ bh, float* __restrict__ u_) {
    const int id = blockIdx.x, t = threadIdx.x;
    if (id < 1024) {              // make_scaled
        const int y = id >> 9;
        const size_t e = ((size_t)(id & 511) * 256 + t) * 8;
        const int z = (int)(e >> 18), rem = (int)(e & 262143);
        const int d = rem >> 9, a0 = rem & 511;
        u16 v[8];
        if (y == 0) {
            *(uint4*)v = *(const uint4*)(WqT16 + rem);
            const float rd = rs_a[(4 + z) * 512 + d];
            const float* rc = rs_a + z * 512 + a0;
            #pragma unroll
            for (int i = 0; i < 8; ++i) v[i] = f2h(h2f(v[i]) * rc[i] * rd);
            *(uint4*)(Wq_z + e) = *(const uint4*)v;
        } else {
            *(uint4*)v = *(const uint4*)(Wf16 + rem);
            const float* rk = rs_a + (4 + z) * 512 + a0;
            #pragma unroll
            for (int i = 0; i < 8; ++i) v[i] = f2h(h2f(v[i]) * rk[i]);
            *(uint4*)(Wf_z + e) = *(const uint4*)v;
        }
    } else if (id < 2048) {       // bias2
        const int w = t >> 6, l = t & 63;
        const int oid = (id - 1024) * 4 + w;
        const int kind = oid >> 11;
        const int z = (oid >> 9) & 3, d = oid & 511;
        const u16* row = (kind == 0 ? WqT16 : Wf16) + (size_t)d * 512;
        const int sb = (kind == 0 ? z : 4 + z) * 512;
        float acc = 0.f;
        #pragma unroll
        for (int i = 0; i < 8; ++i) {
            const int a = l * 8 + i;
            acc += h2f(row[a]) * mu_a[sb + a] * rs_a[sb + a];
        }
        acc = wave_reduce_sum(acc);
        if (l == 0) {
            if (kind == 0) bq[z * 512 + d] = -acc * rs_a[(4 + z) * 512 + d];
            else           bh[z * 512 + d] = bfold0[d] - acc;
        }
    } else {                      // u_big
        const int id2 = id - 2048;                 // 0..255
        const int b = id2 >> 6, xblk = id2 & 63;
        const int w = t >> 6, l = t & 63;
        float4 u0 = *(const float4*)(w_u + l * 8);
        float4 u1 = *(const float4*)(w_u + l * 8 + 4);
        const float4 r0 = *(const float4*)(rs_a + (4 + b) * 512 + l * 8);
        const float4 r1 = *(const float4*)(rs_a + (4 + b) * 512 + l * 8 + 4);
        u0.x *= r0.x; u0.y *= r0.y; u0.z *= r0.z; u0.w *= r0.w;
        u1.x *= r1.x; u1.y *= r1.y; u1.z *= r1.z; u1.w *= r1.w;
        #pragma unroll
        for (int jj = 0; jj < 16; ++jj) {
            const int j = xblk * 64 + w * 16 + jj;
            const u16* row = xs + ((size_t)b * N_SP + j) * C_CH + l * 8;
            f16x8 x = *(const f16x8*)row;
            float acc = (float)x[0] * u0.x + (float)x[1] * u0.y + (float)x[2] * u0.z + (float)x[3] * u0.w
                      + (float)x[4] * u1.x + (float)x[5] * u1.y + (float)x[6] * u1.z + (float)x[7] * u1.w;
            acc = wave_reduce_sum(acc);
            if (l == 0) u_[(size_t)b * N_SP + j] = acc;
        }
    }
}

// ---------------- legacy 4-wave GEMM (32x32x16): kept only for the small 512^3 weight GEMM ----
enum { OUT_F32 = 0, OUT_F16 = 1 };

template<int OUTMODE, bool TABB, bool TABD, int MI, int MJ>
__global__ __launch_bounds__(256) void gemm_bt(
    const u16* __restrict__ A, const u16* __restrict__ B, PtrTab tab,
    float* __restrict__ Df, u16* __restrict__ Dh,
    const float* __restrict__ bias_m, const float* __restrict__ bias_n,
    const float* __restrict__ res,
    int M, int N, int K, int lda, int ldb, int ldd,
    size_t sA, size_t sB, size_t sD, size_t sR, int sBm, int sBn)
{
    constexpr int TM = MI * 64, TN = MJ * 64, BK = 64;
    constexpr int AITS = (TM * BK) / (256 * 8);
    constexpr int BITS = (TN * BK) / (256 * 8);
    __shared__ u16 smem[(TM + TN) * BK];
    u16* As = smem;
    u16* Bs = smem + TM * BK;

    const int t = threadIdx.x;
    const int l = t & 63, w = t >> 6;
    const int m0 = blockIdx.y * TM, n0 = blockIdx.x * TN;
    const size_t zb = blockIdx.z;
    const u16* pA = A + zb * sA + (size_t)m0 * lda;
    const u16* pB = (TABB ? tab.p[zb] : B + zb * sB) + (size_t)n0 * ldb;

    const int wr = (w & 1) * (MI * 32), wc = (w >> 1) * (MJ * 32);

    f32x16 acc[MI][MJ] = {};

    for (int k0 = 0; k0 < K; k0 += BK) {
        #pragma unroll
        for (int it = 0; it < AITS; ++it) {
            const int L = it * 256 + t;
            const int row = L >> 3, c = L & 7;
            const int sc = (c ^ (row & 7)) * 8;
            async_cp16(pA + (size_t)row * lda + k0 + sc, As + L * 8);
        }
        #pragma unroll
        for (int it = 0; it < BITS; ++it) {
            const int L = it * 256 + t;
            const int row = L >> 3, c = L & 7;
            const int sc = (c ^ (row & 7)) * 8;
            async_cp16(pB + (size_t)row * ldb + k0 + sc, Bs + L * 8);
        }
        __syncthreads();
        #pragma unroll
        for (int kk = 0; kk < 4; ++kk) {
            f16x8 af[MI], bf[MJ];
            #pragma unroll
            for (int i = 0; i < MI; ++i) {
                const int row = wr + i * 32 + (l & 31);
                const int ch = ((kk * 2 + (l >> 5)) ^ (row & 7)) * 8;
                af[i] = *(const f16x8*)(As + row * BK + ch);
            }
            #pragma unroll
            for (int j = 0; j < MJ; ++j) {
                const int row = wc + j * 32 + (l & 31);
                const int ch = ((kk * 2 + (l >> 5)) ^ (row & 7)) * 8;
                bf[j] = *(const f16x8*)(Bs + row * BK + ch);
            }
            #pragma unroll
            for (int i = 0; i < MI; ++i)
                #pragma unroll
                for (int j = 0; j < MJ; ++j)
                    acc[i][j] = __builtin_amdgcn_mfma_f32_32x32x16_f16(af[i], bf[j], acc[i][j], 0, 0, 0);
        }
        __syncthreads();
    }

    const int cl = l & 31, rh = (l >> 5) * 4;
    u16* pDh = (OUTMODE == OUT_F16) ? (TABD ? tab.p[zb] : Dh + zb * sD) : nullptr;
    float* pDf = (OUTMODE == OUT_F32) ? (Df + zb * sD) : nullptr;
    #pragma unroll
    for (int i = 0; i < MI; ++i) {
        #pragma unroll
        for (int j = 0; j < MJ; ++j) {
            const int nn = n0 + wc + j * 32 + cl;
            const float bn = bias_n ? bias_n[(size_t)sBn * zb + nn] : 0.f;
            #pragma unroll
            for (int reg = 0; reg < 16; ++reg) {
                const int ml = (reg & 3) + 8 * (reg >> 2) + rh;
                const int mm = m0 + wr + i * 32 + ml;
                float v = acc[i][j][reg] + bn;
                if (bias_m) v += bias_m[(size_t)sBm * zb + mm];
                const size_t off = (size_t)mm * ldd + nn;
                if (OUTMODE == OUT_F32) {
                    if (res) v += res[zb * sR + off];
                    pDf[off] = v;
                } else {
                    pDh[off] = f2h(v);
                }
            }
        }
    }
}

// ======== 8-wave 4-phase GEMM, 16x16x32 frags + FULL 3-bit XOR swizzle (2-way = free) ========
// r6-verified: SQ_LDS_BANK_CONFLICT = 0 with this swizzle. Instantiated at BM=256 only
// (S-GEMM): MF=4 -> 16 MFMA/phase/wave = 620 cyc/CU matrix work per phase, amortizing the
// ~600-800 cyc LDS-drain span (the r6 post-mortem's limiter at 8 MFMA/phase).
template<int OUTMODE, bool TABB, bool TABD, int BM>
__global__ __launch_bounds__(512, 2) void gemm_f(
    const u16* __restrict__ A, const u16* __restrict__ B, PtrTab tab,
    float* __restrict__ Df, u16* __restrict__ Dh,
    const float* __restrict__ bias_m, const float* __restrict__ bias_n,
    const float* __restrict__ res,
    int K, int lda, int ldb, int ldd,
    size_t sA, size_t sB, size_t sD, size_t sR, int sBm, int sBn)
{
    constexpr int BN = 256, BK = 64;
    constexpr int HM = BM / 2;            // A-half rows
    constexpr int MF = BM / 64;           // 16-row m-frags per half per wave
    constexpr int LA = BM / 128;          // gload insts/thread per A-half
    constexpr int LB = 2;                 // gload insts/thread per B-half
    constexpr int LDSH = (BM + BN) * BK;  // u16 per buffer
    __shared__ u16 smem[2 * LDSH];

    const int t = threadIdx.x;
    const int l = t & 63, w = t >> 6;
    const int m0 = blockIdx.y * BM, n0 = blockIdx.x * BN;
    const size_t zb = blockIdx.z;
    const u16* pA = A + zb * sA + (size_t)m0 * lda;
    const u16* pB = (TABB ? tab.p[zb] : B + zb * sB) + (size_t)n0 * ldb;

    const int wr = (w & 1) * (HM / 2);    // wave row offset within an A-half
    const int wc = (w >> 1) * 32;         // wave col offset within a B-half (128)

    f32x4 acc[2 * MF][4] = {};

    auto stageA = [&](int buf, int k0, int half) {
        u16* dst = smem + buf * LDSH;
        #pragma unroll
        for (int it = 0; it < LA; ++it) {
            const int L = it * 512 + t;
            const int row = half * HM + (L >> 3), c = L & 7;
            const int sc = (c ^ (row & 7)) * 8;   // pre-swizzled SOURCE, linear LDS dest
            async_cp16(pA + (size_t)row * lda + k0 + sc, dst + row * BK + c * 8);
        }
    };
    auto stageB = [&](int buf, int k0, int half) {
        u16* dst = smem + buf * LDSH + BM * BK;
        #pragma unroll
        for (int it = 0; it < LB; ++it) {
            const int L = it * 512 + t;
            const int row = half * 128 + (L >> 3), c = L & 7;
            const int sc = (c ^ (row & 7)) * 8;
            async_cp16(pB + (size_t)row * ldb + k0 + sc, dst + row * BK + c * 8);
        }
    };
    auto rdA = [&](const u16* As, int qi, int mf, int kk) -> f16x8 {
        const int row = qi * HM + wr + mf * 16 + (l & 15);
        const int ch = (kk * 4 + (l >> 4)) ^ (row & 7);   // FULL 3-bit XOR -> 2-way free
        return *(const f16x8*)(As + row * BK + ch * 8);
    };
    auto rdB = [&](const u16* Bs, int qj, int nf, int kk) -> f16x8 {
        const int row = qj * 128 + wc + nf * 16 + (l & 15);
        const int ch = (kk * 4 + (l >> 4)) ^ (row & 7);
        return *(const f16x8*)(Bs + row * BK + ch * 8);
    };

    f16x8 af[2][MF][2];   // af[0]=A0 (live p0..p3), af[1]=A1 (live p1..p2)
    f16x8 bf[2][2];       // B0 (p0..p1) then overwritten by B1 (p2..p3)

    const int NT = K / BK;
    // prologue: tile 0 staged in steady-state queue order; leave Bh1 in flight
    stageA(0, 0, 0); stageA(0, 0, 1); stageB(0, 0, 0); stageB(0, 0, 1);
    vmwait<LB>();
    bar();

    for (int tl = 0; tl < NT; ++tl) {
        const int cur = tl & 1, nxt = cur ^ 1;
        const u16* As = smem + cur * LDSH;
        const u16* Bs = As + BM * BK;
        const int k1 = (tl + 1) * BK;
        const bool pf = (tl + 1 < NT);

        // ---- phase 0: A0 x B0 ----
        #pragma unroll
        for (int mf = 0; mf < MF; ++mf) { af[0][mf][0] = rdA(As, 0, mf, 0); af[0][mf][1] = rdA(As, 0, mf, 1); }
        #pragma unroll
        for (int nf = 0; nf < 2; ++nf) { bf[nf][0] = rdB(Bs, 0, nf, 0); bf[nf][1] = rdB(Bs, 0, nf, 1); }
        if (pf) stageA(nxt, k1, 0);
        lgkm0();
        __builtin_amdgcn_s_setprio(1);
        #pragma unroll
        for (int mf = 0; mf < MF; ++mf)
            #pragma unroll
            for (int nf = 0; nf < 2; ++nf) {
                acc[mf][nf] = __builtin_amdgcn_mfma_f32_16x16x32_f16(af[0][mf][0], bf[nf][0], acc[mf][nf], 0, 0, 0);
                acc[mf][nf] = __builtin_amdgcn_mfma_f32_16x16x32_f16(af[0][mf][1], bf[nf][1], acc[mf][nf], 0, 0, 0);
            }
        __builtin_amdgcn_s_setprio(0);
        bar();

        // ---- phase 1: A1 x B0 (B held) ----
        #pragma unroll
        for (int mf = 0; mf < MF; ++mf) { af[1][mf][0] = rdA(As, 1, mf, 0); af[1][mf][1] = rdA(As, 1, mf, 1); }
        if (pf) stageA(nxt, k1, 1);
        lgkm0();
        __builtin_amdgcn_s_setprio(1);
        #pragma unroll
        for (int mf = 0; mf < MF; ++mf)
            #pragma unroll
            for (int nf = 0; nf < 2; ++nf) {
                acc[MF + mf][nf] = __builtin_amdgcn_mfma_f32_16x16x32_f16(af[1][mf][0], bf[nf][0], acc[MF + mf][nf], 0, 0, 0);
                acc[MF + mf][nf] = __builtin_amdgcn_mfma_f32_16x16x32_f16(af[1][mf][1], bf[nf][1], acc[MF + mf][nf], 0, 0, 0);
            }
        __builtin_amdgcn_s_setprio(0);
        if (pf) vmwait<2 * LA>(); else vmwait<0>();   // Bh1(cur) landed; Ah0/Ah1(next) in flight
        bar();

        // ---- phase 2: A1 (held) x B1 ----
        #pragma unroll
        for (int nf = 0; nf < 2; ++nf) { bf[nf][0] = rdB(Bs, 1, nf, 0); bf[nf][1] = rdB(Bs, 1, nf, 1); }
        if (pf) stageB(nxt, k1, 0);
        lgkm0();
        __builtin_amdgcn_s_setprio(1);
        #pragma unroll
        for (int mf = 0; mf < MF; ++mf)
            #pragma unroll
            for (int nf = 0; nf < 2; ++nf) {
                acc[MF + mf][2 + nf] = __builtin_amdgcn_mfma_f32_16x16x32_f16(af[1][mf][0], bf[nf][0], acc[MF + mf][2 + nf], 0, 0, 0);
                acc[MF + mf][2 + nf] = __builtin_amdgcn_mfma_f32_16x16x32_f16(af[1][mf][1], bf[nf][1], acc[MF + mf][2 + nf], 0, 0, 0);
            }
        __builtin_amdgcn_s_setprio(0);
        bar();

        // ---- phase 3: A0 (held) x B1 (held) — no LDS reads ----
        if (pf) stageB(nxt, k1, 1);
        __builtin_amdgcn_s_setprio(1);
        #pragma unroll
        for (int mf = 0; mf < MF; ++mf)
            #pragma unroll
            for (int nf = 0; nf < 2; ++nf) {
                acc[mf][2 + nf] = __builtin_amdgcn_mfma_f32_16x16x32_f16(af[0][mf][0], bf[nf][0], acc[mf][2 + nf], 0, 0, 0);
                acc[mf][2 + nf] = __builtin_amdgcn_mfma_f32_16x16x32_f16(af[0][mf][1], bf[nf][1], acc[mf][2 + nf], 0, 0, 0);
            }
        __builtin_amdgcn_s_setprio(0);
        if (pf) vmwait<LB>();                         // Ah0,Ah1,Bh0(next) landed for next p0/p1
        bar();
    }

    // C/D (16x16): col = lane&15, row = (lane>>4)*4 + reg   (validated r3)
    const int cl = l & 15, rh = (l >> 4) * 4;
    u16* pDh = (OUTMODE == OUT_F16) ? (TABD ? tab.p[zb] : Dh + zb * sD) : nullptr;
    float* pDf = (OUTMODE == OUT_F32) ? (Df + zb * sD) : nullptr;
    #pragma unroll
    for (int qi = 0; qi < 2; ++qi) {
        #pragma unroll
        for (int qj = 0; qj < 2; ++qj) {
            #pragma unroll
            for (int mf = 0; mf < MF; ++mf) {
                #pragma unroll
                for (int nf = 0; nf < 2; ++nf) {
                    const int nn = n0 + qj * 128 + wc + nf * 16 + cl;
                    const float bn = bias_n ? bias_n[(size_t)sBn * zb + nn] : 0.f;
                    const f32x4 a4 = acc[qi * MF + mf][qj * 2 + nf];
                    #pragma unroll
                    for (int reg = 0; reg < 4; ++reg) {
                        const int mm = m0 + qi * HM + wr + mf * 16 + rh + reg;
                        float v = a4[reg] + bn;
                        if (bias_m) v += bias_m[(size_t)sBm * zb + mm];
                        const size_t off = (size_t)mm * ldd + nn;
                        if (OUTMODE == OUT_F32) {
                            if (res) v += res[zb * sR + off];
                            pDf[off] = v;
                        } else {
                            pDh[off] = f2h(v);
                        }
                    }
                }
            }
        }
    }
}

// ======== 2-phase variant, BM=128 fixed: 16 MFMA/phase (thin-M GEMMs: q', hc, PV) ========
// Same swizzle/frag/epilogue as gemm_f (r6-verified, conflicts=0). Tour merged to 2 phases:
//   ph0: read A0,A1,B0 (12 reads) -> MFMA (A0+A1) x B0 (16) ; stage {Ah0,Ah1,Bh0}(nxt)
//   ph1: read B1 (4)              -> MFMA (A0+A1) x B1 (16) ; stage {Bh1}(nxt)
// Queue/tile: [Ah0(1),Ah1(1),Bh0(2)] @ph0, [Bh1(2)] @ph1.
// end-ph0 vmwait<4>: drains Bh1(cur) (needed ph1), keeps {A,Bh0}(nxt)=4 in flight.
// end-ph1 vmwait<2>: drains {A,Bh0}(nxt) (needed next ph0), keeps Bh1(nxt) in flight.
// Per-wave vmwait + trailing barrier => block-wide (symmetric load sequences).
template<int OUTMODE, bool TABB, bool TABD>
__global__ __launch_bounds__(512, 2) void gemm_f2(
    const u16* __restrict__ A, const u16* __restrict__ B, PtrTab tab,
    float* __restrict__ Df, u16* __restrict__ Dh,
    const float* __restrict__ bias_m, const float* __restrict__ bias_n,
    const float* __restrict__ res,
    int K, int lda, int ldb, int ldd,
    size_t sA, size_t sB, size_t sD, size_t sR, int sBm, int sBn)
{
    constexpr int BM = 128, BN = 256, BK = 64;
    constexpr int HM = 64, MF = 2, LA = 1, LB = 2;
    constexpr int LDSH = (BM + BN) * BK;
    __shared__ u16 smem[2 * LDSH];

    const int t = threadIdx.x;
    const int l = t & 63, w = t >> 6;
    const int m0 = blockIdx.y * BM, n0 = blockIdx.x * BN;
    const size_t zb = blockIdx.z;
    const u16* pA = A + zb * sA + (size_t)m0 * lda;
    const u16* pB = (TABB ? tab.p[zb] : B + zb * sB) + (size_t)n0 * ldb;

    const int wr = (w & 1) * (HM / 2);
    const int wc = (w >> 1) * 32;

    f32x4 acc[2 * MF][4] = {};

    auto stageA = [&](int buf, int k0, int half) {
        u16* dst = smem + buf * LDSH;
        #pragma unroll
        for (int it = 0; it < LA; ++it) {
            const int L = it * 512 + t;
            const int row = half * HM + (L >> 3), c = L & 7;
            const int sc = (c ^ (row & 7)) * 8;
            async_cp16(pA + (size_t)row * lda + k0 + sc, dst + row * BK + c * 8);
        }
    };
    auto stageB = [&](int buf, int k0, int half) {
        u16* dst = smem + buf * LDSH + BM * BK;
        #pragma unroll
        for (int it = 0; it < LB; ++it) {
            const int L = it * 512 + t;
            const int row = half * 128 + (L >> 3), c = L & 7;
            const int sc = (c ^ (row & 7)) * 8;
            async_cp16(pB + (size_t)row * ldb + k0 + sc, dst + row * BK + c * 8);
        }
    };
    auto rdA = [&](const u16* As, int qi, int mf, int kk) -> f16x8 {
        const int row = qi * HM + wr + mf * 16 + (l & 15);
        const int ch = (kk * 4 + (l >> 4)) ^ (row & 7);
        return *(const f16x8*)(As + row * BK + ch * 8);
    };
    auto rdB = [&](const u16* Bs, int qj, int nf, int kk) -> f16x8 {
        const int row = qj * 128 + wc + nf * 16 + (l & 15);
        const int ch = (kk * 4 + (l >> 4)) ^ (row & 7);
        return *(const f16x8*)(Bs + row * BK + ch * 8);
    };

    f16x8 af[2][MF][2];   // A0,A1 held across both phases
    f16x8 bf[2][2];       // B0 (ph0) then B1 (ph1)

    const int NT = K / BK;
    // prologue: queue [Ah0,Ah1,Bh0, Bh1]; ph0 needs A+Bh0 -> leave Bh1(2) flying
    stageA(0, 0, 0); stageA(0, 0, 1); stageB(0, 0, 0); stageB(0, 0, 1);
    vmwait<2>();
    bar();

    for (int tl = 0; tl < NT; ++tl) {
        const int cur = tl & 1, nxt = cur ^ 1;
        const u16* As = smem + cur * LDSH;
        const u16* Bs = As + BM * BK;
        const int k1 = (tl + 1) * BK;
        const bool pf = (tl + 1 < NT);

        // ---- phase 0: (A0+A1) x B0 ----
        #pragma unroll
        for (int qi = 0; qi < 2; ++qi)
            #pragma unroll
            for (int mf = 0; mf < MF; ++mf) {
                af[qi][mf][0] = rdA(As, qi, mf, 0);
                af[qi][mf][1] = rdA(As, qi, mf, 1);
            }
        #pragma unroll
        for (int nf = 0; nf < 2; ++nf) { bf[nf][0] = rdB(Bs, 0, nf, 0); bf[nf][1] = rdB(Bs, 0, nf, 1); }
        if (pf) { stageA(nxt, k1, 0); stageA(nxt, k1, 1); stageB(nxt, k1, 0); }
        lgkm0();
        __builtin_amdgcn_s_setprio(1);
        #pragma unroll
        for (int qi = 0; qi < 2; ++qi)
            #pragma unroll
            for (int mf = 0; mf < MF; ++mf)
                #pragma unroll
                for (int nf = 0; nf < 2; ++nf) {
                    acc[qi * MF + mf][nf] = __builtin_amdgcn_mfma_f32_16x16x32_f16(af[qi][mf][0], bf[nf][0], acc[qi * MF + mf][nf], 0, 0, 0);
                    acc[qi * MF + mf][nf] = __builtin_amdgcn_mfma_f32_16x16x32_f16(af[qi][mf][1], bf[nf][1], acc[qi * MF + mf][nf], 0, 0, 0);
                }
        __builtin_amdgcn_s_setprio(0);
        if (pf) vmwait<4>(); else vmwait<0>();   // drain Bh1(cur); keep {A,Bh0}(nxt)
        bar();

        // ---- phase 1: (A0+A1) x B1 (A held) ----
        #pragma unroll
        for (int nf = 0; nf < 2; ++nf) { bf[nf][0] = rdB(Bs, 1, nf, 0); bf[nf][1] = rdB(Bs, 1, nf, 1); }
        if (pf) stageB(nxt, k1, 1);
        lgkm0();
        __builtin_amdgcn_s_setprio(1);
        #pragma unroll
        for (int qi = 0; qi < 2; ++qi)
            #pragma unroll
            for (int mf = 0; mf < MF; ++mf)
                #pragma unroll
                for (int nf = 0; nf < 2; ++nf) {
                    acc[qi * MF + mf][2 + nf] = __builtin_amdgcn_mfma_f32_16x16x32_f16(af[qi][mf][0], bf[nf][0], acc[qi * MF + mf][2 + nf], 0, 0, 0);
                    acc[qi * MF + mf][2 + nf] = __builtin_amdgcn_mfma_f32_16x16x32_f16(af[qi][mf][1], bf[nf][1], acc[qi * MF + mf][2 + nf], 0, 0, 0);
                }
        __builtin_amdgcn_s_setprio(0);
        if (pf) vmwait<2>();                     // drain {A,Bh0}(nxt); keep Bh1(nxt)
        bar();
    }

    // C/D (16x16): col = lane&15, row = (lane>>4)*4 + reg
    const int cl = l & 15, rh = (l >> 4) * 4;
    u16* pDh = (OUTMODE == OUT_F16) ? (TABD ? tab.p[zb] : Dh + zb * sD) : nullptr;
    float* pDf = (OUTMODE == OUT_F32) ? (Df + zb * sD) : nullptr;
    #pragma unroll
    for (int qi = 0; qi < 2; ++qi) {
        #pragma unroll
        for (int qj = 0; qj < 2; ++qj) {
            #pragma unroll
            for (int mf = 0; mf < MF; ++mf) {
                #pragma unroll
                for (int nf = 0; nf < 2; ++nf) {
                    const int nn = n0 + qj * 128 + wc + nf * 16 + cl;
                    const float bn = bias_n ? bias_n[(size_t)sBn * zb + nn] : 0.f;
                    const f32x4 a4 = acc[qi * MF + mf][qj * 2 + nf];
                    #pragma unroll
                    for (int reg = 0; reg < 4; ++reg) {
                        const int mm = m0 + qi * HM + wr + mf * 16 + rh + reg;
                        float v = a4[reg] + bn;
                        if (bias_m) v += bias_m[(size_t)sBm * zb + mm];
                        const size_t off = (size_t)mm * ldd + nn;
                        if (OUTMODE == OUT_F32) {
                            if (res) v += res[zb * sR + off];
                            pDf[off] = v;
                        } else {
                            pDh[off] = f2h(v);
                        }
                    }
                }
            }
        }
    }
}

// ---------------- softmax row-wise, fp16 in-place ----------------
__global__ __launch_bounds__(256) void softmax_kernel(PtrTab tab) {
    u16* row = tab.p[blockIdx.y] + (size_t)blockIdx.x * N_SP;
    const int t = threadIdx.x;
    u16 raw[16];
    *(uint4*)(raw + 0) = *(const uint4*)(row + t * 16);
    *(uint4*)(raw + 8) = *(const uint4*)(row + t * 16 + 8);
    float v[16];
    float mx = -1e30f;
    #pragma unroll
    for (int i = 0; i < 16; ++i) { v[i] = h2f(raw[i]); mx = fmaxf(mx, v[i]); }
    mx = wave_reduce_max(mx);
    __shared__ float red[4];
    const int wave = t >> 6;
    if ((t & 63) == 0) red[wave] = mx;
    __syncthreads();
    mx = fmaxf(fmaxf(red[0], red[1]), fmaxf(red[2], red[3]));
    float sum = 0.f;
    #pragma unroll
    for (int i = 0; i < 16; ++i) { v[i] = __expf(v[i] - mx); sum += v[i]; }
    sum = wave_reduce_sum(sum);
    __syncthreads();
    if ((t & 63) == 0) red[wave] = sum;
    __syncthreads();
    const float inv = 1.f / (red[0] + red[1] + red[2] + red[3]);
    #pragma unroll
    for (int i = 0; i < 16; ++i) raw[i] = f2h(v[i] * inv);
    *(uint4*)(row + t * 16)     = *(const uint4*)(raw + 0);
    *(uint4*)(row + t * 16 + 8) = *(const uint4*)(raw + 8);
}

extern "C" void kernel_launch(void* const* d_in, const int* in_sizes, int n_in,
                              void* d_out, int out_size, void* d_ws, size_t ws_size,
                              hipStream_t stream) {
    const float* f_c   = (const float*)d_in[0];
    const float* f_s   = (const float*)d_in[1];
    const float* W_c1  = (const float*)d_in[2];
    const float* b_c1  = (const float*)d_in[3];
    const float* W_s1  = (const float*)d_in[4];
    const float* b_s1  = (const float*)d_in[5]; (void)b_s1;   // softmax-invariant, dropped
    const float* W_s2  = (const float*)d_in[6];
    const float* b_s2  = (const float*)d_in[7];
    const float* W_csc = (const float*)d_in[8];
    const float* b_csc = (const float*)d_in[9];

    const size_t PB = (size_t)N_SP * C_CH;      // 2M elems per batch plane
    const size_t M1 = 1024 * 1024;

    u16* ws   = (u16*)d_ws;
    u16* Xs   = ws;                 // raw fp16 [b][j][c]   0..8M
    u16* q_   = ws + 8 * M1;        // q'[b][i][d]          8..16M
    u16* hc   = ws + 16 * M1;       // hc[b][o][j]          16..24M
    u16* Xc   = ws + 24 * M1;       // raw fp16 (dead after q'-conv; S3 aliases)
    u16* S3   = ws + 24 * M1;
    u16* S0   = ws + 40 * M1;
    u16* S1   = ws + 56 * M1;
    u16* S2   = ws + 72 * M1;
    u16* Wbase= ws + 88 * M1;       // 6 x 262144: Ws1T, Wcs16, Wc1T, Ws2T, WqT16, Wf16
    u16* WqT16= Wbase + 4 * 262144;
    u16* Wf16 = Wbase + 5 * 262144;
    u16* Wq_z = Wbase + 6 * 262144; // 4 x 256K
    u16* Wf_z = Wq_z + 1048576;     // 4 x 256K
    float* f32b = (float*)(ws + 92 * M1);
    float* part_s  = f32b;          // 4096
    float* part_ss = f32b + 4096;
    float* mu_a    = f32b + 8192;
    float* rs_a    = f32b + 12288;
    float* w_u     = f32b + 16384;  // 512
    float* bfold0  = f32b + 16896;  // 512
    float* bq      = f32b + 17408;  // 2048
    float* bh      = f32b + 19456;  // 2048
    float* u_      = f32b + 21504;  // 4*4096

    PtrTab Stab; Stab.p[0] = S0; Stab.p[1] = S1; Stab.p[2] = S2; Stab.p[3] = S3;
    PtrTab tab0 = Stab;

    hipMemsetAsync(part_s, 0, 2 * 4096 * sizeof(float), stream);

    transpose_cast_stats<<<dim3(64, 8, 8), 256, 0, stream>>>(f_c, f_s, Xc, Xs, part_s, part_ss);

    // weight transforms + stats finalize + small gemvs, one launch
    prep1<<<dim3(8, 8, 5), 256, 0, stream>>>(W_c1, W_s1, W_s2, W_csc, b_c1, b_s2, b_csc,
                                             Wbase, part_s, part_ss, mu_a, rs_a, w_u, bfold0);

    // WqT[d][a] = sum_o Ws1T[d][o] Wc1T[a][o]; Wfold[o][k] = sum_c Wcs16[o][c] Ws2T[k][c]
    gemm_bt<OUT_F16, false, false, 2, 2><<<dim3(4, 4, 2), 256, 0, stream>>>(
        Wbase, Wbase + 2 * 262144, tab0, nullptr, WqT16, nullptr, nullptr, nullptr,
        512, 512, 512, 512, 512, 512, 262144, 262144, 262144, 0, 0, 0);

    // per-batch scaled weights + folded biases + u vector, one launch
    prep2<<<2304, 256, 0, stream>>>(WqT16, Wf16, Xs, mu_a, rs_a, bfold0, w_u,
                                    Wq_z, Wf_z, bq, bh, u_);

    // q'[b][i][d] = sum_a Xc_raw[b][i][a] Wq_z[b][d][a] + bq[b][d]
    gemm_f2<OUT_F16, false, false><<<dim3(2, 32, B_SZ), 512, 0, stream>>>(
        Xc, Wq_z, tab0, nullptr, q_, nullptr, bq, nullptr,
        C_CH, C_CH, C_CH, C_CH, PB, 262144, PB, 0, 0, 512);
    // hc[b][o][j] = sum_k Wf_z[b][o][k] Xs_raw[b][j][k] + bh[b][o]
    gemm_f2<OUT_F16, false, false><<<dim3(16, 4, B_SZ), 512, 0, stream>>>(
        Wf_z, Xs, tab0, nullptr, hc, bh, nullptr, nullptr,
        C_CH, C_CH, C_CH, N_SP, 262144, PB, PB, 0, 512, 0);

    // S_b[i][j] = sum_d q'[i][d] Xs_raw[j][d] + u[b][j]
    // BM=256: 16 MFMA/phase/wave (the round-7 lever), conflicts already 0
    gemm_f<OUT_F16, false, true, 256><<<dim3(16, 16, B_SZ), 512, 0, stream>>>(
        q_, Xs, Stab, nullptr, nullptr, nullptr, u_, nullptr,
        C_CH, C_CH, C_CH, N_SP, PB, PB, 0, 0, 0, N_SP);

    softmax_kernel<<<dim3(N_SP, B_SZ), 256, 0, stream>>>(Stab);

    // out[b][o][i] = sum_j hc[o][j] P[i][j] + f_c
    gemm_f2<OUT_F32, true, false><<<dim3(16, 4, B_SZ), 512, 0, stream>>>(
        hc, nullptr, Stab, (float*)d_out, nullptr, nullptr, nullptr, f_c,
        N_SP, N_SP, N_SP, N_SP, PB, 0, PB, PB, 0, 0);
}